// Round 8
// baseline (2257.285 us; speedup 1.0000x reference)
//
#include <hip/hip_runtime.h>

#define NROWS 32
#define NPB   262144
#define LOG2_NPB 18
#define K_SEL 13107u
#define NTOT  (NROWS * NPB)

// XLA-CPU reduce vectorization factor (f32 lanes). Candidates: 8 (ymm), 4, 32.
#define VF 8

// ---------- ws layout (byte offsets) ----------
#define OFF_PART  0        // float[32][VF] lane partials (reused mean/var)
#define OFF_MEAN  4096     // float[32]
#define OFF_BETA  4224     // float[32]
#define OFF_CNT   4352     // uint[4][32][256] = 131072 (zeroed)
#define OFF_PFX   135424   // uint[32] (zeroed)
#define OFF_RANK  135552   // uint[32] (zeroed)
#define OFF_ACTS  1048576  // float[NTOT] optional cache
#define WS_NEED_ACTS (OFF_ACTS + (size_t)NTOT * 4)

// ======== XLA:CPU f32 log twin (GenerateVF32Log / Eigen plog, Cephes) ========
// Unfused mul+add at every MulAdd (VectorSupportLibrary semantics, no FMA).
__device__ __forceinline__ float xla_logf(float xf) {
    unsigned b = __float_as_uint(xf);
    float e = (float)(int)((b >> 23) - 126u);
    float m = __uint_as_float((b & 0x007FFFFFu) | 0x3F000000u);   // [0.5,1)
    bool mk = m < 0.707106781186547524f;                          // 0x3F3504F3
    float tmp = mk ? m : 0.0f;
    if (mk) e = __fsub_rn(e, 1.0f);
    float x = __fadd_rn(__fsub_rn(m, 1.0f), tmp);                 // (m-1)+tmp
    float z  = __fmul_rn(x, x);
    float x3 = __fmul_rn(z, x);
    float y  = __fadd_rn(__fmul_rn( 7.0376836292e-2f, x), -1.1514610310e-1f);
    float y1 = __fadd_rn(__fmul_rn(-1.2420140846e-1f, x),  1.4249322787e-1f);
    float y2 = __fadd_rn(__fmul_rn( 2.0000714765e-1f, x), -2.4999993993e-1f);
    y  = __fadd_rn(__fmul_rn(y,  x),  1.1676998740e-1f);
    y1 = __fadd_rn(__fmul_rn(y1, x), -1.6668057665e-1f);
    y2 = __fadd_rn(__fmul_rn(y2, x),  3.3333331174e-1f);
    y  = __fadd_rn(__fmul_rn(y, x3), y1);
    y  = __fadd_rn(__fmul_rn(y, x3), y2);
    y  = __fmul_rn(y, x3);
    y  = __fadd_rn(__fmul_rn(e, -2.12194440e-4f), y);             // + e*q1
    y  = __fsub_rn(y, __fmul_rn(z, 0.5f));                        // - 0.5*z
    x  = __fadd_rn(x, y);
    x  = __fadd_rn(__fmul_rn(e, 0.693359375f), x);                // + e*q2
    return x;
}

// act key: bits of relu(x + beta*(-log(-log u))), order-isomorphic (non-neg)
__device__ __forceinline__ unsigned act_key(float xf, float uf, float bt) {
    float i1 = xla_logf(uf);
    float i3 = xla_logf(-i1);
    float g  = -i3;
    float a  = fmaxf(__fadd_rn(xf, __fmul_rn(bt, g)), 0.0f);
    unsigned key = __float_as_uint(a);
    if (key == 0x80000000u) key = 0u;
    return key;
}

// ======== XLA-CPU vectorized-reduce twin: VF lane chains + halving tree ======
__global__ void k_lanesum(const float* __restrict__ x, const float* __restrict__ mean_in,
                          float* __restrict__ partial, int mode) {
    int row = blockIdx.x;
    int lane = threadIdx.x;
    if (lane >= VF) return;
    const float* xr = x + (size_t)row * NPB;
    float mean = (mode == 1) ? mean_in[row] : 0.0f;
    float p = 0.0f;                                   // reduce init = 0
    for (int i = 0; i < NPB / VF; i++) {
        float v = xr[(size_t)i * VF + lane];
        if (mode == 1) { float c = __fsub_rn(v, mean); v = __fmul_rn(c, c); }
        p = __fadd_rn(p, v);                          // strict sequential chain
    }
    partial[row * VF + lane] = p;
}

__global__ void k_finish(const float* __restrict__ partial, float* __restrict__ outv, int mode) {
    int row = threadIdx.x;
    if (row >= NROWS) return;
    const float* p = partial + row * VF;
    // halving shuffle tree: VF -> VF/2 -> ... -> 1 (exact XLA AddReduce order)
    float t[VF];
    for (int j = 0; j < VF; j++) t[j] = p[j];
    for (int w = VF / 2; w >= 1; w >>= 1)
        for (int j = 0; j < w; j++) t[j] = __fadd_rn(t[j], t[j + w]);
    float S = t[0];
    if (mode == 0) {
        outv[row] = __fdiv_rn(S, 262144.0f);          // mean = sum/N
    } else {
        float var = __fdiv_rn(S, 262143.0f);          // sum(centered^2)/(N-ddof)
        float sd  = __fsqrt_rn(var);
        outv[row] = __fdiv_rn(sd, (float)(0.1 + 1e-6));
    }
}

// ================= exact MSB radix-select (4 x 8-bit digits) =================
__device__ const unsigned pass_himask[4] = {0x00000000u, 0xFF000000u, 0xFFFF0000u, 0xFFFFFF00u};
__device__ const int      pass_shift[4]  = {24, 16, 8, 0};

__global__ void k_hist(const float* __restrict__ x, const float* __restrict__ u,
                       const float* __restrict__ beta,
                       const float* __restrict__ acts_in, float* __restrict__ acts_out,
                       unsigned* __restrict__ cnt, const unsigned* __restrict__ prefix, int p) {
    __shared__ unsigned lh[256];
    int row = blockIdx.x >> 4, blk = blockIdx.x & 15;
    lh[threadIdx.x] = 0;
    __syncthreads();
    float bt = beta[row];
    unsigned pfx = (p > 0) ? prefix[row] : 0u;
    unsigned hm  = pass_himask[p];
    int sh = pass_shift[p];
    size_t base = (size_t)row * NPB + (size_t)blk * (NPB / 16);
    for (int i = threadIdx.x; i < NPB / 16; i += 256) {
        unsigned key;
        if (acts_in) key = __float_as_uint(acts_in[base + i]);
        else         key = act_key(x[base + i], u[base + i], bt);
        if (acts_out) acts_out[base + i] = __uint_as_float(key);
        if ((key & hm) == pfx)
            atomicAdd(&lh[(key >> sh) & 255u], 1u);
    }
    __syncthreads();
    if (lh[threadIdx.x])
        atomicAdd(&cnt[(size_t)row * 256 + threadIdx.x], lh[threadIdx.x]);
}

__global__ void k_sel(const unsigned* __restrict__ cnt, unsigned* prefix, unsigned* rank, int p) {
    if (threadIdx.x != 0) return;
    int row = blockIdx.x;
    unsigned r   = (p == 0) ? K_SEL : rank[row];
    unsigned pfx = (p == 0) ? 0u : prefix[row];
    const unsigned* h = cnt + (size_t)row * 256;
    int sh = pass_shift[p];
    unsigned c = 0;
    for (int v = 255; v >= 0; v--) {
        unsigned hv = h[v];
        if (c + hv >= r) {
            prefix[row] = pfx | ((unsigned)v << sh);
            rank[row]   = r - c;
            return;
        }
        c += hv;
    }
}

__global__ void k_write(const float* __restrict__ x, const float* __restrict__ u,
                        const float* __restrict__ beta, const float* __restrict__ acts_in,
                        const unsigned* __restrict__ prefix, float* __restrict__ out) {
    size_t e = (size_t)blockIdx.x * 256 + threadIdx.x;
    int row = (int)(e >> LOG2_NPB);
    unsigned key;
    if (acts_in) key = __float_as_uint(acts_in[e]);
    else         key = act_key(x[e], u[e], beta[row]);
    unsigned kb = prefix[row];                        // bits of kth largest
    bool m = (key >= kb);
    out[e] = m ? __uint_as_float(key) : 0.0f;
    out[(size_t)NTOT + e] = m ? 1.0f : 0.0f;
}

extern "C" void kernel_launch(void* const* d_in, const int* in_sizes, int n_in,
                              void* d_out, int out_size, void* d_ws, size_t ws_size,
                              hipStream_t stream) {
    const float* x = (const float*)d_in[0];
    const float* u = (const float*)d_in[1];
    float* out = (float*)d_out;
    char* ws = (char*)d_ws;

    float*    partial = (float*)(ws + OFF_PART);
    float*    meanv   = (float*)(ws + OFF_MEAN);
    float*    beta    = (float*)(ws + OFF_BETA);
    unsigned* cnt     = (unsigned*)(ws + OFF_CNT);
    unsigned* prefix  = (unsigned*)(ws + OFF_PFX);
    unsigned* rank    = (unsigned*)(ws + OFF_RANK);
    float*    acts    = (ws_size >= WS_NEED_ACTS) ? (float*)(ws + OFF_ACTS) : nullptr;

    hipMemsetAsync(ws + OFF_CNT, 0, 131328, stream);  // cnt + pfx + rank

    k_lanesum<<<NROWS, 64, 0, stream>>>(x, nullptr, partial, 0);
    k_finish <<<1, 64, 0, stream>>>(partial, meanv, 0);
    k_lanesum<<<NROWS, 64, 0, stream>>>(x, meanv, partial, 1);
    k_finish <<<1, 64, 0, stream>>>(partial, beta, 1);

    for (int p = 0; p < 4; p++) {
        const float* ain  = (p == 0) ? nullptr : acts;
        float*       aout = (p == 0) ? acts : nullptr;
        k_hist<<<NROWS * 16, 256, 0, stream>>>(x, u, beta, ain, aout,
                                               cnt + (size_t)p * NROWS * 256, prefix, p);
        k_sel <<<NROWS, 64, 0, stream>>>(cnt + (size_t)p * NROWS * 256, prefix, rank, p);
    }

    k_write<<<NTOT / 256, 256, 0, stream>>>(x, u, beta, acts, prefix, out);
}

// Round 9
// 737.486 us; speedup vs baseline: 3.0608x; 3.0608x over previous
//
#include <hip/hip_runtime.h>

#define NROWS 32
#define NPB   262144
#define LOG2_NPB 18
#define K_SEL 13107u
#define NTOT  (NROWS * NPB)
#define VF 8

// k_std tiling
#define TILE   4096              // floats per staged tile (16 KB)
#define NT     (NPB / TILE)      // 64 tiles
#define CPT    (TILE / VF)       // 512 chain adds per tile per lane
#define LROW   516               // padded LDS row (floats); 516*4 % 16 == 0

// ---------- ws layout (byte offsets) ----------
#define OFF_BETA  4224     // float[32]
#define OFF_CNT   4352     // uint[4][32][256] = 131072 (zeroed)
#define OFF_PFX   135424   // uint[32] (zeroed)
#define OFF_RANK  135552   // uint[32] (zeroed)
#define OFF_ACTS  1048576  // float[NTOT] optional cache
#define WS_NEED_ACTS (OFF_ACTS + (size_t)NTOT * 4)

// ======== XLA:CPU f32 log twin (GenerateVF32Log / Eigen plog, Cephes) ========
// Unfused mul+add at every MulAdd. FROZEN: bits validated round 8.
__device__ __forceinline__ float xla_logf(float xf) {
    unsigned b = __float_as_uint(xf);
    float e = (float)(int)((b >> 23) - 126u);
    float m = __uint_as_float((b & 0x007FFFFFu) | 0x3F000000u);   // [0.5,1)
    bool mk = m < 0.707106781186547524f;
    float tmp = mk ? m : 0.0f;
    if (mk) e = __fsub_rn(e, 1.0f);
    float x = __fadd_rn(__fsub_rn(m, 1.0f), tmp);
    float z  = __fmul_rn(x, x);
    float x3 = __fmul_rn(z, x);
    float y  = __fadd_rn(__fmul_rn( 7.0376836292e-2f, x), -1.1514610310e-1f);
    float y1 = __fadd_rn(__fmul_rn(-1.2420140846e-1f, x),  1.4249322787e-1f);
    float y2 = __fadd_rn(__fmul_rn( 2.0000714765e-1f, x), -2.4999993993e-1f);
    y  = __fadd_rn(__fmul_rn(y,  x),  1.1676998740e-1f);
    y1 = __fadd_rn(__fmul_rn(y1, x), -1.6668057665e-1f);
    y2 = __fadd_rn(__fmul_rn(y2, x),  3.3333331174e-1f);
    y  = __fadd_rn(__fmul_rn(y, x3), y1);
    y  = __fadd_rn(__fmul_rn(y, x3), y2);
    y  = __fmul_rn(y, x3);
    y  = __fadd_rn(__fmul_rn(e, -2.12194440e-4f), y);
    y  = __fsub_rn(y, __fmul_rn(z, 0.5f));
    x  = __fadd_rn(x, y);
    x  = __fadd_rn(__fmul_rn(e, 0.693359375f), x);
    return x;
}

__device__ __forceinline__ unsigned act_key(float xf, float uf, float bt) {
    float i1 = xla_logf(uf);
    float i3 = xla_logf(-i1);
    float g  = -i3;
    float a  = fmaxf(__fadd_rn(xf, __fmul_rn(bt, g)), 0.0f);
    unsigned key = __float_as_uint(a);
    if (key == 0x80000000u) key = 0u;
    return key;
}

// ======== k_std: XLA VF=8 reduce twin, latency-hidden, bit-identical ========
// One block per row. Stagers transpose tiles into LDS (double-buffered,
// issue-early/write-late); 8 chain lanes run the exact sequential __fadd_rn
// chains; thread 0 runs the exact VF=8 halving tree + mean/var/beta ops.
__global__ __launch_bounds__(256) void k_std(const float* __restrict__ x,
                                             float* __restrict__ beta_out) {
    int row = blockIdx.x;
    int tid = threadIdx.x;
    const float* xr = x + (size_t)row * NPB;
    __shared__ float buf[2][VF][LROW];
    __shared__ float partial[VF];
    __shared__ float mean_sh;

    for (int mode = 0; mode < 2; mode++) {
        float mean = (mode == 1) ? mean_sh : 0.0f;
        // prologue: stage tile 0
        {
            float4 r[4];
            #pragma unroll
            for (int s = 0; s < 4; s++)
                r[s] = ((const float4*)xr)[tid + s * 256];
            #pragma unroll
            for (int s = 0; s < 4; s++) {
                int g4 = (tid + s * 256) * 4;
                #pragma unroll
                for (int q = 0; q < 4; q++) {
                    int g = g4 + q;
                    float v = (&r[s].x)[q];
                    if (mode) { float c = __fsub_rn(v, mean); v = __fmul_rn(c, c); }
                    buf[0][g & 7][g >> 3] = v;
                }
            }
        }
        __syncthreads();

        float p = 0.0f;
        for (int t = 0; t < NT; t++) {
            // issue next tile's global loads early
            float4 r[4];
            if (t + 1 < NT) {
                const float* src = xr + (size_t)(t + 1) * TILE;
                #pragma unroll
                for (int s = 0; s < 4; s++)
                    r[s] = ((const float4*)src)[tid + s * 256];
            }
            // serial chain on current tile (exact XLA lane order)
            if (tid < VF) {
                const float* srcl = &buf[t & 1][tid][0];
                #pragma unroll 8
                for (int i = 0; i < CPT; i++)
                    p = __fadd_rn(p, srcl[i]);
            }
            // write next tile (transposed) into the other buffer
            if (t + 1 < NT) {
                #pragma unroll
                for (int s = 0; s < 4; s++) {
                    int g4 = (tid + s * 256) * 4;
                    #pragma unroll
                    for (int q = 0; q < 4; q++) {
                        int g = g4 + q;
                        float v = (&r[s].x)[q];
                        if (mode) { float c = __fsub_rn(v, mean); v = __fmul_rn(c, c); }
                        buf[(t + 1) & 1][g & 7][g >> 3] = v;
                    }
                }
            }
            __syncthreads();
        }
        if (tid < VF) partial[tid] = p;
        __syncthreads();
        if (tid == 0) {
            float tr[VF];
            for (int j = 0; j < VF; j++) tr[j] = partial[j];
            for (int w = VF / 2; w >= 1; w >>= 1)
                for (int j = 0; j < w; j++) tr[j] = __fadd_rn(tr[j], tr[j + w]);
            float S = tr[0];
            if (mode == 0) {
                mean_sh = __fdiv_rn(S, 262144.0f);
            } else {
                float var = __fdiv_rn(S, 262143.0f);
                float sd  = __fsqrt_rn(var);
                beta_out[row] = __fdiv_rn(sd, (float)(0.1 + 1e-6));
            }
        }
        __syncthreads();
    }
}

// ================= exact MSB radix-select (4 x 8-bit digits) =================
__device__ const unsigned pass_himask[4] = {0x00000000u, 0xFF000000u, 0xFFFF0000u, 0xFFFFFF00u};
__device__ const int      pass_shift[4]  = {24, 16, 8, 0};

__global__ void k_hist(const float* __restrict__ x, const float* __restrict__ u,
                       const float* __restrict__ beta,
                       const float* __restrict__ acts_in, float* __restrict__ acts_out,
                       unsigned* __restrict__ cnt, const unsigned* __restrict__ prefix, int p) {
    __shared__ unsigned lh[256];
    int row = blockIdx.x >> 4, blk = blockIdx.x & 15;
    lh[threadIdx.x] = 0;
    __syncthreads();
    float bt = beta[row];
    unsigned pfx = (p > 0) ? prefix[row] : 0u;
    unsigned hm  = pass_himask[p];
    int sh = pass_shift[p];
    size_t base = (size_t)row * NPB + (size_t)blk * (NPB / 16);
    for (int i = threadIdx.x; i < NPB / 16; i += 256) {
        unsigned key;
        if (acts_in) key = __float_as_uint(acts_in[base + i]);
        else         key = act_key(x[base + i], u[base + i], bt);
        if (acts_out) acts_out[base + i] = __uint_as_float(key);
        if ((key & hm) == pfx)
            atomicAdd(&lh[(key >> sh) & 255u], 1u);
    }
    __syncthreads();
    if (lh[threadIdx.x])
        atomicAdd(&cnt[(size_t)row * 256 + threadIdx.x], lh[threadIdx.x]);
}

__global__ void k_sel(const unsigned* __restrict__ cnt, unsigned* prefix, unsigned* rank, int p) {
    if (threadIdx.x != 0) return;
    int row = blockIdx.x;
    unsigned r   = (p == 0) ? K_SEL : rank[row];
    unsigned pfx = (p == 0) ? 0u : prefix[row];
    const unsigned* h = cnt + (size_t)row * 256;
    int sh = pass_shift[p];
    unsigned c = 0;
    for (int v = 255; v >= 0; v--) {
        unsigned hv = h[v];
        if (c + hv >= r) {
            prefix[row] = pfx | ((unsigned)v << sh);
            rank[row]   = r - c;
            return;
        }
        c += hv;
    }
}

__global__ void k_write(const float* __restrict__ x, const float* __restrict__ u,
                        const float* __restrict__ beta, const float* __restrict__ acts_in,
                        const unsigned* __restrict__ prefix, float* __restrict__ out) {
    size_t e = (size_t)blockIdx.x * 256 + threadIdx.x;
    int row = (int)(e >> LOG2_NPB);
    unsigned key;
    if (acts_in) key = __float_as_uint(acts_in[e]);
    else         key = act_key(x[e], u[e], beta[row]);
    unsigned kb = prefix[row];
    bool m = (key >= kb);
    out[e] = m ? __uint_as_float(key) : 0.0f;
    out[(size_t)NTOT + e] = m ? 1.0f : 0.0f;
}

extern "C" void kernel_launch(void* const* d_in, const int* in_sizes, int n_in,
                              void* d_out, int out_size, void* d_ws, size_t ws_size,
                              hipStream_t stream) {
    const float* x = (const float*)d_in[0];
    const float* u = (const float*)d_in[1];
    float* out = (float*)d_out;
    char* ws = (char*)d_ws;

    float*    beta    = (float*)(ws + OFF_BETA);
    unsigned* cnt     = (unsigned*)(ws + OFF_CNT);
    unsigned* prefix  = (unsigned*)(ws + OFF_PFX);
    unsigned* rank    = (unsigned*)(ws + OFF_RANK);
    float*    acts    = (ws_size >= WS_NEED_ACTS) ? (float*)(ws + OFF_ACTS) : nullptr;

    hipMemsetAsync(ws + OFF_CNT, 0, 131328, stream);  // cnt + pfx + rank

    k_std<<<NROWS, 256, 0, stream>>>(x, beta);

    for (int p = 0; p < 4; p++) {
        const float* ain  = (p == 0) ? nullptr : acts;
        float*       aout = (p == 0) ? acts : nullptr;
        k_hist<<<NROWS * 16, 256, 0, stream>>>(x, u, beta, ain, aout,
                                               cnt + (size_t)p * NROWS * 256, prefix, p);
        k_sel <<<NROWS, 64, 0, stream>>>(cnt + (size_t)p * NROWS * 256, prefix, rank, p);
    }

    k_write<<<NTOT / 256, 256, 0, stream>>>(x, u, beta, acts, prefix, out);
}

// Round 10
// 548.221 us; speedup vs baseline: 4.1175x; 1.3452x over previous
//
#include <hip/hip_runtime.h>

#define NROWS 32
#define NPB   262144
#define LOG2_NPB 18
#define K_SEL 13107u
#define NTOT  (NROWS * NPB)
#define VF 8

// k_std tiling
#define TILE   8192              // floats per staged tile (32 KB)
#define NT     (NPB / TILE)      // 32 tiles
#define CPL    (TILE / VF)       // 1024 chain adds per tile per lane
#define LROW   1028              // padded LDS row; 1028*4 = 4112 = 257*16

// ---------- ws layout (byte offsets) ----------
#define OFF_BETA  4224     // float[32]
#define OFF_CNT   4352     // uint[4][32][256] = 131072 (zeroed)
#define OFF_PFX   135424   // uint[32] (zeroed)
#define OFF_RANK  135552   // uint[32] (zeroed)
#define OFF_ACTS  1048576  // float[NTOT] optional cache
#define WS_NEED_ACTS (OFF_ACTS + (size_t)NTOT * 4)

// ======== XLA:CPU f32 log twin (GenerateVF32Log / Eigen plog, Cephes) ========
// Unfused mul+add at every MulAdd. FROZEN: bits validated round 8.
__device__ __forceinline__ float xla_logf(float xf) {
    unsigned b = __float_as_uint(xf);
    float e = (float)(int)((b >> 23) - 126u);
    float m = __uint_as_float((b & 0x007FFFFFu) | 0x3F000000u);   // [0.5,1)
    bool mk = m < 0.707106781186547524f;
    float tmp = mk ? m : 0.0f;
    if (mk) e = __fsub_rn(e, 1.0f);
    float x = __fadd_rn(__fsub_rn(m, 1.0f), tmp);
    float z  = __fmul_rn(x, x);
    float x3 = __fmul_rn(z, x);
    float y  = __fadd_rn(__fmul_rn( 7.0376836292e-2f, x), -1.1514610310e-1f);
    float y1 = __fadd_rn(__fmul_rn(-1.2420140846e-1f, x),  1.4249322787e-1f);
    float y2 = __fadd_rn(__fmul_rn( 2.0000714765e-1f, x), -2.4999993993e-1f);
    y  = __fadd_rn(__fmul_rn(y,  x),  1.1676998740e-1f);
    y1 = __fadd_rn(__fmul_rn(y1, x), -1.6668057665e-1f);
    y2 = __fadd_rn(__fmul_rn(y2, x),  3.3333331174e-1f);
    y  = __fadd_rn(__fmul_rn(y, x3), y1);
    y  = __fadd_rn(__fmul_rn(y, x3), y2);
    y  = __fmul_rn(y, x3);
    y  = __fadd_rn(__fmul_rn(e, -2.12194440e-4f), y);
    y  = __fsub_rn(y, __fmul_rn(z, 0.5f));
    x  = __fadd_rn(x, y);
    x  = __fadd_rn(__fmul_rn(e, 0.693359375f), x);
    return x;
}

__device__ __forceinline__ unsigned act_key(float xf, float uf, float bt) {
    float i1 = xla_logf(uf);
    float i3 = xla_logf(-i1);
    float g  = -i3;
    float a  = fmaxf(__fadd_rn(xf, __fmul_rn(bt, g)), 0.0f);
    unsigned key = __float_as_uint(a);
    if (key == 0x80000000u) key = 0u;
    return key;
}

// ======== k_std: XLA VF=8 reduce twin, latency-hidden, bit-identical ========
// One block per row. Stagers transpose tiles into LDS (double-buffered);
// 8 chain lanes run the exact sequential __fadd_rn chains with register
// double-buffered ds_read_b128 prefetch; thread 0 runs the exact VF=8
// halving tree + mean/var/beta ops.
__global__ __launch_bounds__(256) void k_std(const float* __restrict__ x,
                                             float* __restrict__ beta_out) {
    int row = blockIdx.x;
    int tid = threadIdx.x;
    const float* xr = x + (size_t)row * NPB;
    __shared__ __align__(16) float buf[2][VF][LROW];   // 65792 B
    __shared__ float partial[VF];
    __shared__ float mean_sh;

    for (int mode = 0; mode < 2; mode++) {
        float mean = (mode == 1) ? mean_sh : 0.0f;
        // prologue: stage tile 0 (8 float4 per thread)
        {
            float4 r[8];
            #pragma unroll
            for (int s = 0; s < 8; s++)
                r[s] = ((const float4*)xr)[tid + s * 256];
            #pragma unroll
            for (int s = 0; s < 8; s++) {
                int g4 = (tid + s * 256) * 4;
                #pragma unroll
                for (int q = 0; q < 4; q++) {
                    int g = g4 + q;
                    float v = (&r[s].x)[q];
                    if (mode) { float c = __fsub_rn(v, mean); v = __fmul_rn(c, c); }
                    buf[0][g & 7][g >> 3] = v;
                }
            }
        }
        __syncthreads();

        float p = 0.0f;
        for (int t = 0; t < NT; t++) {
            // issue next tile's global loads early
            float4 r[8];
            if (t + 1 < NT) {
                const float* src = xr + (size_t)(t + 1) * TILE;
                #pragma unroll
                for (int s = 0; s < 8; s++)
                    r[s] = ((const float4*)src)[tid + s * 256];
            }
            // serial chain on current tile (exact XLA lane order), A/B reg dbuf
            if (tid < VF) {
                const float4* srcl = (const float4*)&buf[t & 1][tid][0];
                float4 A[8], B[8];
                #pragma unroll
                for (int j = 0; j < 8; j++) A[j] = srcl[j];
                for (int c = 0; c < CPL / 32; c += 2) {
                    #pragma unroll
                    for (int j = 0; j < 8; j++) B[j] = srcl[(c + 1) * 8 + j];
                    #pragma unroll
                    for (int j = 0; j < 8; j++) {
                        p = __fadd_rn(p, A[j].x); p = __fadd_rn(p, A[j].y);
                        p = __fadd_rn(p, A[j].z); p = __fadd_rn(p, A[j].w);
                    }
                    if (c + 2 < CPL / 32) {
                        #pragma unroll
                        for (int j = 0; j < 8; j++) A[j] = srcl[(c + 2) * 8 + j];
                    }
                    #pragma unroll
                    for (int j = 0; j < 8; j++) {
                        p = __fadd_rn(p, B[j].x); p = __fadd_rn(p, B[j].y);
                        p = __fadd_rn(p, B[j].z); p = __fadd_rn(p, B[j].w);
                    }
                }
            }
            // write next tile (transposed) into the other buffer
            if (t + 1 < NT) {
                #pragma unroll
                for (int s = 0; s < 8; s++) {
                    int g4 = (tid + s * 256) * 4;
                    #pragma unroll
                    for (int q = 0; q < 4; q++) {
                        int g = g4 + q;
                        float v = (&r[s].x)[q];
                        if (mode) { float c = __fsub_rn(v, mean); v = __fmul_rn(c, c); }
                        buf[(t + 1) & 1][g & 7][g >> 3] = v;
                    }
                }
            }
            __syncthreads();
        }
        if (tid < VF) partial[tid] = p;
        __syncthreads();
        if (tid == 0) {
            float tr[VF];
            for (int j = 0; j < VF; j++) tr[j] = partial[j];
            for (int w = VF / 2; w >= 1; w >>= 1)
                for (int j = 0; j < w; j++) tr[j] = __fadd_rn(tr[j], tr[j + w]);
            float S = tr[0];
            if (mode == 0) {
                mean_sh = __fdiv_rn(S, 262144.0f);
            } else {
                float var = __fdiv_rn(S, 262143.0f);
                float sd  = __fsqrt_rn(var);
                beta_out[row] = __fdiv_rn(sd, (float)(0.1 + 1e-6));
            }
        }
        __syncthreads();
    }
}

// ================= exact MSB radix-select (4 x 8-bit digits) =================
__device__ const unsigned pass_himask[4] = {0x00000000u, 0xFF000000u, 0xFFFF0000u, 0xFFFFFF00u};
__device__ const int      pass_shift[4]  = {24, 16, 8, 0};

__global__ void k_hist(const float* __restrict__ x, const float* __restrict__ u,
                       const float* __restrict__ beta,
                       const float* __restrict__ acts_in, float* __restrict__ acts_out,
                       unsigned* __restrict__ cnt, const unsigned* __restrict__ prefix, int p) {
    __shared__ unsigned lh[256];
    int row = blockIdx.x >> 4, blk = blockIdx.x & 15;
    lh[threadIdx.x] = 0;
    __syncthreads();
    float bt = beta[row];
    unsigned pfx = (p > 0) ? prefix[row] : 0u;
    unsigned hm  = pass_himask[p];
    int sh = pass_shift[p];
    size_t base = (size_t)row * NPB + (size_t)blk * (NPB / 16);
    for (int i = threadIdx.x; i < NPB / 16; i += 256) {
        unsigned key;
        if (acts_in) key = __float_as_uint(acts_in[base + i]);
        else         key = act_key(x[base + i], u[base + i], bt);
        if (acts_out) acts_out[base + i] = __uint_as_float(key);
        if ((key & hm) == pfx)
            atomicAdd(&lh[(key >> sh) & 255u], 1u);
    }
    __syncthreads();
    if (lh[threadIdx.x])
        atomicAdd(&cnt[(size_t)row * 256 + threadIdx.x], lh[threadIdx.x]);
}

__global__ void k_sel(const unsigned* __restrict__ cnt, unsigned* prefix, unsigned* rank, int p) {
    if (threadIdx.x != 0) return;
    int row = blockIdx.x;
    unsigned r   = (p == 0) ? K_SEL : rank[row];
    unsigned pfx = (p == 0) ? 0u : prefix[row];
    const unsigned* h = cnt + (size_t)row * 256;
    int sh = pass_shift[p];
    unsigned c = 0;
    for (int v = 255; v >= 0; v--) {
        unsigned hv = h[v];
        if (c + hv >= r) {
            prefix[row] = pfx | ((unsigned)v << sh);
            rank[row]   = r - c;
            return;
        }
        c += hv;
    }
}

__global__ void k_write(const float* __restrict__ x, const float* __restrict__ u,
                        const float* __restrict__ beta, const float* __restrict__ acts_in,
                        const unsigned* __restrict__ prefix, float* __restrict__ out) {
    size_t e = (size_t)blockIdx.x * 256 + threadIdx.x;
    int row = (int)(e >> LOG2_NPB);
    unsigned key;
    if (acts_in) key = __float_as_uint(acts_in[e]);
    else         key = act_key(x[e], u[e], beta[row]);
    unsigned kb = prefix[row];
    bool m = (key >= kb);
    out[e] = m ? __uint_as_float(key) : 0.0f;
    out[(size_t)NTOT + e] = m ? 1.0f : 0.0f;
}

extern "C" void kernel_launch(void* const* d_in, const int* in_sizes, int n_in,
                              void* d_out, int out_size, void* d_ws, size_t ws_size,
                              hipStream_t stream) {
    const float* x = (const float*)d_in[0];
    const float* u = (const float*)d_in[1];
    float* out = (float*)d_out;
    char* ws = (char*)d_ws;

    float*    beta    = (float*)(ws + OFF_BETA);
    unsigned* cnt     = (unsigned*)(ws + OFF_CNT);
    unsigned* prefix  = (unsigned*)(ws + OFF_PFX);
    unsigned* rank    = (unsigned*)(ws + OFF_RANK);
    float*    acts    = (ws_size >= WS_NEED_ACTS) ? (float*)(ws + OFF_ACTS) : nullptr;

    hipMemsetAsync(ws + OFF_CNT, 0, 131328, stream);  // cnt + pfx + rank

    k_std<<<NROWS, 256, 0, stream>>>(x, beta);

    for (int p = 0; p < 4; p++) {
        const float* ain  = (p == 0) ? nullptr : acts;
        float*       aout = (p == 0) ? acts : nullptr;
        k_hist<<<NROWS * 16, 256, 0, stream>>>(x, u, beta, ain, aout,
                                               cnt + (size_t)p * NROWS * 256, prefix, p);
        k_sel <<<NROWS, 64, 0, stream>>>(cnt + (size_t)p * NROWS * 256, prefix, rank, p);
    }

    k_write<<<NTOT / 256, 256, 0, stream>>>(x, u, beta, acts, prefix, out);
}

// Round 11
// 354.323 us; speedup vs baseline: 6.3707x; 1.5472x over previous
//
#include <hip/hip_runtime.h>

#define NROWS 32
#define NPB   262144
#define LOG2_NPB 18
#define K_SEL 13107u
#define NTOT  (NROWS * NPB)
#define VF 8

// k_std tiling
#define TILE   8192              // floats per staged tile (32 KB)
#define NT     (NPB / TILE)      // 32 tiles
#define CPL    (TILE / VF)       // 1024 chain floats per tile per lane
#define NCH    (CPL / 64)        // 16 chunks of 64 floats
#define LROW   1028              // padded LDS row; 1028*4 = 4112 B, 16B-aligned
#define GBLK   224               // g-precompute blocks appended to k_std grid

// ---------- ws layout (byte offsets) ----------
#define OFF_BETA  4224     // float[32]
#define OFF_CNT   4352     // uint[4][32][256] = 131072 (zeroed)
#define OFF_PFX   135424   // uint[32] (zeroed)
#define OFF_RANK  135552   // uint[32] (zeroed)
#define OFF_ACTS  1048576                    // float[NTOT] acts-key cache
#define OFF_G     (OFF_ACTS + (size_t)NTOT*4) // float[NTOT] g cache
#define WS_NEED_ACTS (OFF_ACTS + (size_t)NTOT * 4)
#define WS_NEED_G    (OFF_G    + (size_t)NTOT * 4)

// ======== XLA:CPU f32 log twin (GenerateVF32Log / Eigen plog, Cephes) ========
// Unfused mul+add at every MulAdd. FROZEN: bits validated round 8.
__device__ __forceinline__ float xla_logf(float xf) {
    unsigned b = __float_as_uint(xf);
    float e = (float)(int)((b >> 23) - 126u);
    float m = __uint_as_float((b & 0x007FFFFFu) | 0x3F000000u);   // [0.5,1)
    bool mk = m < 0.707106781186547524f;
    float tmp = mk ? m : 0.0f;
    if (mk) e = __fsub_rn(e, 1.0f);
    float x = __fadd_rn(__fsub_rn(m, 1.0f), tmp);
    float z  = __fmul_rn(x, x);
    float x3 = __fmul_rn(z, x);
    float y  = __fadd_rn(__fmul_rn( 7.0376836292e-2f, x), -1.1514610310e-1f);
    float y1 = __fadd_rn(__fmul_rn(-1.2420140846e-1f, x),  1.4249322787e-1f);
    float y2 = __fadd_rn(__fmul_rn( 2.0000714765e-1f, x), -2.4999993993e-1f);
    y  = __fadd_rn(__fmul_rn(y,  x),  1.1676998740e-1f);
    y1 = __fadd_rn(__fmul_rn(y1, x), -1.6668057665e-1f);
    y2 = __fadd_rn(__fmul_rn(y2, x),  3.3333331174e-1f);
    y  = __fadd_rn(__fmul_rn(y, x3), y1);
    y  = __fadd_rn(__fmul_rn(y, x3), y2);
    y  = __fmul_rn(y, x3);
    y  = __fadd_rn(__fmul_rn(e, -2.12194440e-4f), y);
    y  = __fsub_rn(y, __fmul_rn(z, 0.5f));
    x  = __fadd_rn(x, y);
    x  = __fadd_rn(__fmul_rn(e, 0.693359375f), x);
    return x;
}

__device__ __forceinline__ float g_of(float uf) {
    float i1 = xla_logf(uf);
    float i3 = xla_logf(-i1);
    return -i3;
}

__device__ __forceinline__ unsigned key_from_g(float xf, float gf, float bt) {
    float a = fmaxf(__fadd_rn(xf, __fmul_rn(bt, gf)), 0.0f);
    unsigned key = __float_as_uint(a);
    if (key == 0x80000000u) key = 0u;
    return key;
}

__device__ __forceinline__ unsigned act_key(float xf, float uf, float bt) {
    return key_from_g(xf, g_of(uf), bt);
}

// ======== k_std: XLA VF=8 reduce twin + fused g-precompute ========
// Blocks 0..31: one per row. Wave 0 lanes 0-7 run the exact sequential
// __fadd_rn chains (64-float chunks, A/B register prefetch); threads 64-255
// stage+transpose tiles into double-buffered LDS. Blocks 32+: compute
// g = -log(-log u) into ws (independent of beta -> overlaps the chain).
__global__ __launch_bounds__(256) void k_std(const float* __restrict__ x,
                                             const float* __restrict__ u,
                                             float* __restrict__ beta_out,
                                             float* __restrict__ g_out) {
    __shared__ __align__(16) float buf[2][VF][LROW];   // 65792 B
    __shared__ float partial[VF];
    __shared__ float mean_sh;
    int tid = threadIdx.x;

    if (blockIdx.x >= NROWS) {                 // ---- g-precompute blocks ----
        if (!g_out) return;
        const float4* u4 = (const float4*)u;
        float4* g4 = (float4*)g_out;
        int idx = (blockIdx.x - NROWS) * 256 + tid;
        int stride = GBLK * 256;
        for (int i = idx; i < NTOT / 4; i += stride) {
            float4 uu = u4[i];
            float4 gg;
            gg.x = g_of(uu.x); gg.y = g_of(uu.y);
            gg.z = g_of(uu.z); gg.w = g_of(uu.w);
            g4[i] = gg;
        }
        return;
    }

    int row = blockIdx.x;
    const float* xr = x + (size_t)row * NPB;

    for (int mode = 0; mode < 2; mode++) {
        float mean = (mode == 1) ? mean_sh : 0.0f;
        // prologue: stagers (tid>=64) stage tile 0
        if (tid >= 64) {
            int st = tid - 64;                          // 0..191
            for (int f = st; f < TILE / 4; f += 192) {
                float4 v4 = ((const float4*)xr)[f];
                #pragma unroll
                for (int q = 0; q < 4; q++) {
                    int g = f * 4 + q;
                    float v = (&v4.x)[q];
                    if (mode) { float c = __fsub_rn(v, mean); v = __fmul_rn(c, c); }
                    buf[0][g & 7][g >> 3] = v;
                }
            }
        }
        __syncthreads();

        float p = 0.0f;
        for (int t = 0; t < NT; t++) {
            if (tid < VF) {
                // pure chain wave: exact XLA lane order, A/B 64-float prefetch
                const float4* srcl = (const float4*)&buf[t & 1][tid][0];
                float4 A[16], B[16];
                #pragma unroll
                for (int j = 0; j < 16; j++) A[j] = srcl[j];
                #pragma unroll
                for (int c = 0; c < NCH; c += 2) {
                    #pragma unroll
                    for (int j = 0; j < 16; j++) B[j] = srcl[(c + 1) * 16 + j];
                    #pragma unroll
                    for (int j = 0; j < 16; j++) {
                        p = __fadd_rn(p, A[j].x); p = __fadd_rn(p, A[j].y);
                        p = __fadd_rn(p, A[j].z); p = __fadd_rn(p, A[j].w);
                    }
                    if (c + 2 < NCH) {
                        #pragma unroll
                        for (int j = 0; j < 16; j++) A[j] = srcl[(c + 2) * 16 + j];
                    }
                    #pragma unroll
                    for (int j = 0; j < 16; j++) {
                        p = __fadd_rn(p, B[j].x); p = __fadd_rn(p, B[j].y);
                        p = __fadd_rn(p, B[j].z); p = __fadd_rn(p, B[j].w);
                    }
                }
            } else if (tid >= 64 && t + 1 < NT) {
                // stagers: load + transpose next tile into the other buffer
                int st = tid - 64;
                const float* src = xr + (size_t)(t + 1) * TILE;
                for (int f = st; f < TILE / 4; f += 192) {
                    float4 v4 = ((const float4*)src)[f];
                    #pragma unroll
                    for (int q = 0; q < 4; q++) {
                        int g = f * 4 + q;
                        float v = (&v4.x)[q];
                        if (mode) { float c = __fsub_rn(v, mean); v = __fmul_rn(c, c); }
                        buf[(t + 1) & 1][g & 7][g >> 3] = v;
                    }
                }
            }
            __syncthreads();
        }
        if (tid < VF) partial[tid] = p;
        __syncthreads();
        if (tid == 0) {
            float tr[VF];
            for (int j = 0; j < VF; j++) tr[j] = partial[j];
            for (int w = VF / 2; w >= 1; w >>= 1)
                for (int j = 0; j < w; j++) tr[j] = __fadd_rn(tr[j], tr[j + w]);
            float S = tr[0];
            if (mode == 0) {
                mean_sh = __fdiv_rn(S, 262144.0f);
            } else {
                float var = __fdiv_rn(S, 262143.0f);
                float sd  = __fsqrt_rn(var);
                beta_out[row] = __fdiv_rn(sd, (float)(0.1 + 1e-6));
            }
        }
        __syncthreads();
    }
}

// ================= exact MSB radix-select (4 x 8-bit digits) =================
__device__ const unsigned pass_himask[4] = {0x00000000u, 0xFF000000u, 0xFFFF0000u, 0xFFFFFF00u};
__device__ const int      pass_shift[4]  = {24, 16, 8, 0};

// pass 0: vectorized key build (x4 + g4), acts cache write, zero-skip hist
__global__ void k_hist0(const float* __restrict__ x, const float* __restrict__ u,
                        const float* __restrict__ g, const float* __restrict__ beta,
                        float* __restrict__ acts_out, unsigned* __restrict__ cnt) {
    __shared__ unsigned lh[256];
    int row = blockIdx.x >> 4, blk = blockIdx.x & 15;
    lh[threadIdx.x] = 0;
    __syncthreads();
    float bt = beta[row];
    size_t base4 = ((size_t)row * NPB + (size_t)blk * (NPB / 16)) / 4;
    const float4* x4 = (const float4*)x;
    const float4* g4 = (const float4*)g;
    float4* a4 = (float4*)acts_out;
    unsigned zc = 0;
    for (int i = threadIdx.x; i < NPB / 16 / 4; i += 256) {
        float4 xx = x4[base4 + i];
        unsigned k[4];
        if (g) {
            float4 gg = g4[base4 + i];
            k[0] = key_from_g(xx.x, gg.x, bt); k[1] = key_from_g(xx.y, gg.y, bt);
            k[2] = key_from_g(xx.z, gg.z, bt); k[3] = key_from_g(xx.w, gg.w, bt);
        } else {
            const float4 uu = ((const float4*)u)[base4 + i];
            k[0] = act_key(xx.x, uu.x, bt); k[1] = act_key(xx.y, uu.y, bt);
            k[2] = act_key(xx.z, uu.z, bt); k[3] = act_key(xx.w, uu.w, bt);
        }
        if (acts_out) {
            float4 av;
            av.x = __uint_as_float(k[0]); av.y = __uint_as_float(k[1]);
            av.z = __uint_as_float(k[2]); av.w = __uint_as_float(k[3]);
            a4[base4 + i] = av;
        }
        #pragma unroll
        for (int q = 0; q < 4; q++) {
            if (k[q]) atomicAdd(&lh[k[q] >> 24], 1u);
            else      zc++;
        }
    }
    if (zc) atomicAdd(&lh[0], zc);
    __syncthreads();
    if (lh[threadIdx.x])
        atomicAdd(&cnt[(size_t)row * 256 + threadIdx.x], lh[threadIdx.x]);
}

// passes 1-3: vectorized acts read, conditional (rare) atomics
__global__ void k_histN(const float* __restrict__ x, const float* __restrict__ u,
                        const float* __restrict__ beta, const float* __restrict__ acts_in,
                        unsigned* __restrict__ cnt, const unsigned* __restrict__ prefix, int p) {
    __shared__ unsigned lh[256];
    int row = blockIdx.x >> 4, blk = blockIdx.x & 15;
    lh[threadIdx.x] = 0;
    __syncthreads();
    unsigned pfx = prefix[row];
    unsigned hm  = pass_himask[p];
    int sh = pass_shift[p];
    size_t base = (size_t)row * NPB + (size_t)blk * (NPB / 16);
    if (acts_in) {
        const float4* a4 = (const float4*)(acts_in + base);
        for (int i = threadIdx.x; i < NPB / 16 / 4; i += 256) {
            float4 av = a4[i];
            #pragma unroll
            for (int q = 0; q < 4; q++) {
                unsigned key = __float_as_uint((&av.x)[q]);
                if ((key & hm) == pfx)
                    atomicAdd(&lh[(key >> sh) & 255u], 1u);
            }
        }
    } else {
        float bt = beta[row];
        for (int i = threadIdx.x; i < NPB / 16; i += 256) {
            unsigned key = act_key(x[base + i], u[base + i], bt);
            if ((key & hm) == pfx)
                atomicAdd(&lh[(key >> sh) & 255u], 1u);
        }
    }
    __syncthreads();
    if (lh[threadIdx.x])
        atomicAdd(&cnt[(size_t)row * 256 + threadIdx.x], lh[threadIdx.x]);
}

__global__ void k_sel(const unsigned* __restrict__ cnt, unsigned* prefix, unsigned* rank, int p) {
    if (threadIdx.x != 0) return;
    int row = blockIdx.x;
    unsigned r   = (p == 0) ? K_SEL : rank[row];
    unsigned pfx = (p == 0) ? 0u : prefix[row];
    const unsigned* h = cnt + (size_t)row * 256;
    int sh = pass_shift[p];
    unsigned c = 0;
    for (int v = 255; v >= 0; v--) {
        unsigned hv = h[v];
        if (c + hv >= r) {
            prefix[row] = pfx | ((unsigned)v << sh);
            rank[row]   = r - c;
            return;
        }
        c += hv;
    }
}

__global__ void k_write(const float* __restrict__ x, const float* __restrict__ u,
                        const float* __restrict__ beta, const float* __restrict__ acts_in,
                        const unsigned* __restrict__ prefix, float* __restrict__ out) {
    size_t e4 = (size_t)blockIdx.x * 256 + threadIdx.x;     // float4 index
    int row = (int)(e4 >> (LOG2_NPB - 2));
    unsigned kb = prefix[row];
    unsigned k[4];
    if (acts_in) {
        float4 av = ((const float4*)acts_in)[e4];
        #pragma unroll
        for (int q = 0; q < 4; q++) k[q] = __float_as_uint((&av.x)[q]);
    } else {
        float bt = beta[row];
        const float4 xx = ((const float4*)x)[e4];
        const float4 uu = ((const float4*)u)[e4];
        k[0] = act_key(xx.x, uu.x, bt); k[1] = act_key(xx.y, uu.y, bt);
        k[2] = act_key(xx.z, uu.z, bt); k[3] = act_key(xx.w, uu.w, bt);
    }
    float4 sp, mk;
    #pragma unroll
    for (int q = 0; q < 4; q++) {
        bool m = (k[q] >= kb);
        (&sp.x)[q] = m ? __uint_as_float(k[q]) : 0.0f;
        (&mk.x)[q] = m ? 1.0f : 0.0f;
    }
    ((float4*)out)[e4] = sp;
    ((float4*)(out + NTOT))[e4] = mk;
}

extern "C" void kernel_launch(void* const* d_in, const int* in_sizes, int n_in,
                              void* d_out, int out_size, void* d_ws, size_t ws_size,
                              hipStream_t stream) {
    const float* x = (const float*)d_in[0];
    const float* u = (const float*)d_in[1];
    float* out = (float*)d_out;
    char* ws = (char*)d_ws;

    float*    beta    = (float*)(ws + OFF_BETA);
    unsigned* cnt     = (unsigned*)(ws + OFF_CNT);
    unsigned* prefix  = (unsigned*)(ws + OFF_PFX);
    unsigned* rank    = (unsigned*)(ws + OFF_RANK);
    float*    acts    = (ws_size >= WS_NEED_ACTS) ? (float*)(ws + OFF_ACTS) : nullptr;
    float*    g       = (ws_size >= WS_NEED_G)    ? (float*)(ws + OFF_G)    : nullptr;

    hipMemsetAsync(ws + OFF_CNT, 0, 131328, stream);  // cnt + pfx + rank

    k_std<<<NROWS + GBLK, 256, 0, stream>>>(x, u, beta, g);

    k_hist0<<<NROWS * 16, 256, 0, stream>>>(x, u, g, beta, acts, cnt);
    k_sel  <<<NROWS, 64, 0, stream>>>(cnt, prefix, rank, 0);
    for (int p = 1; p < 4; p++) {
        k_histN<<<NROWS * 16, 256, 0, stream>>>(x, u, beta, acts,
                                                cnt + (size_t)p * NROWS * 256, prefix, p);
        k_sel  <<<NROWS, 64, 0, stream>>>(cnt + (size_t)p * NROWS * 256, prefix, rank, p);
    }

    k_write<<<NTOT / 4 / 256, 256, 0, stream>>>(x, u, beta, acts, prefix, out);
}

// Round 13
// 351.572 us; speedup vs baseline: 6.4205x; 1.0078x over previous
//
#include <hip/hip_runtime.h>

#define NROWS 32
#define NPB   262144
#define LOG2_NPB 18
#define K_SEL 13107u
#define NTOT  (NROWS * NPB)
#define VF 8

// k_std tiling
#define TILE   8192              // floats per staged tile (32 KB)
#define NT     (NPB / TILE)      // 32 tiles
#define CPL    (TILE / VF)       // 1024 chain floats per tile per lane
#define NCH    (CPL / 64)        // 16 chunks of 64 floats
#define LROW   1028              // padded LDS row; 1028*4 = 4112 B, 16B-aligned
#define GBLK   224               // g-precompute blocks appended to k_std grid

typedef __attribute__((ext_vector_type(4))) float f32x4;

// ---------- ws layout (byte offsets) ----------
#define OFF_BETA  4224     // float[32]
#define OFF_CNT   4352     // uint[4][32][256] = 131072 (zeroed)
#define OFF_PFX   135424   // uint[32] (zeroed)
#define OFF_RANK  135552   // uint[32] (zeroed)
#define OFF_ACTS  1048576                    // float[NTOT] acts-key cache
#define OFF_G     (OFF_ACTS + (size_t)NTOT*4) // float[NTOT] g cache
#define WS_NEED_ACTS (OFF_ACTS + (size_t)NTOT * 4)
#define WS_NEED_G    (OFF_G    + (size_t)NTOT * 4)

// ======== XLA:CPU f32 log twin (GenerateVF32Log / Eigen plog, Cephes) ========
// Unfused mul+add at every MulAdd. FROZEN: bits validated round 8.
__device__ __forceinline__ float xla_logf(float xf) {
    unsigned b = __float_as_uint(xf);
    float e = (float)(int)((b >> 23) - 126u);
    float m = __uint_as_float((b & 0x007FFFFFu) | 0x3F000000u);   // [0.5,1)
    bool mk = m < 0.707106781186547524f;
    float tmp = mk ? m : 0.0f;
    if (mk) e = __fsub_rn(e, 1.0f);
    float x = __fadd_rn(__fsub_rn(m, 1.0f), tmp);
    float z  = __fmul_rn(x, x);
    float x3 = __fmul_rn(z, x);
    float y  = __fadd_rn(__fmul_rn( 7.0376836292e-2f, x), -1.1514610310e-1f);
    float y1 = __fadd_rn(__fmul_rn(-1.2420140846e-1f, x),  1.4249322787e-1f);
    float y2 = __fadd_rn(__fmul_rn( 2.0000714765e-1f, x), -2.4999993993e-1f);
    y  = __fadd_rn(__fmul_rn(y,  x),  1.1676998740e-1f);
    y1 = __fadd_rn(__fmul_rn(y1, x), -1.6668057665e-1f);
    y2 = __fadd_rn(__fmul_rn(y2, x),  3.3333331174e-1f);
    y  = __fadd_rn(__fmul_rn(y, x3), y1);
    y  = __fadd_rn(__fmul_rn(y, x3), y2);
    y  = __fmul_rn(y, x3);
    y  = __fadd_rn(__fmul_rn(e, -2.12194440e-4f), y);
    y  = __fsub_rn(y, __fmul_rn(z, 0.5f));
    x  = __fadd_rn(x, y);
    x  = __fadd_rn(__fmul_rn(e, 0.693359375f), x);
    return x;
}

__device__ __forceinline__ float g_of(float uf) {
    float i1 = xla_logf(uf);
    float i3 = xla_logf(-i1);
    return -i3;
}

__device__ __forceinline__ unsigned key_from_g(float xf, float gf, float bt) {
    float a = fmaxf(__fadd_rn(xf, __fmul_rn(bt, gf)), 0.0f);
    unsigned key = __float_as_uint(a);
    if (key == 0x80000000u) key = 0u;
    return key;
}

__device__ __forceinline__ unsigned act_key(float xf, float uf, float bt) {
    return key_from_g(xf, g_of(uf), bt);
}

// ======== k_std: XLA VF=8 reduce twin + fused g-precompute ========
// Blocks 0..31: one per row. Wave 0 lanes 0-7 run the exact sequential
// __fadd_rn chains; threads 64-255 stage+transpose tiles into double-buffered
// LDS. Blocks 32+: g = -log(-log u) precompute (beta-independent -> overlaps).
// __launch_bounds__(256,1): 1 block/CU -> larger VGPR budget for A/B buffers.
// R12 BUG FIXED: stager branch must be guarded by tid >= 64 (threads 8..63
// were running it with negative offsets, corrupting LDS -> wrong beta).
__global__ __launch_bounds__(256, 1) void k_std(const float* __restrict__ x,
                                                const float* __restrict__ u,
                                                float* __restrict__ beta_out,
                                                float* __restrict__ g_out) {
    __shared__ __align__(16) float buf[2][VF][LROW];   // 65792 B
    __shared__ float partial[VF];
    __shared__ float mean_sh;
    int tid = threadIdx.x;

    if (blockIdx.x >= NROWS) {                 // ---- g-precompute blocks ----
        if (!g_out) return;
        const float4* u4 = (const float4*)u;
        float4* g4 = (float4*)g_out;
        int idx = (blockIdx.x - NROWS) * 256 + tid;
        int stride = GBLK * 256;
        for (int i = idx; i < NTOT / 4; i += stride) {
            float4 uu = u4[i];
            float4 gg;
            gg.x = g_of(uu.x); gg.y = g_of(uu.y);
            gg.z = g_of(uu.z); gg.w = g_of(uu.w);
            g4[i] = gg;
        }
        return;
    }

    int row = blockIdx.x;
    const float* xr = x + (size_t)row * NPB;

    for (int mode = 0; mode < 2; mode++) {
        float mean = (mode == 1) ? mean_sh : 0.0f;
        // prologue: stagers (tid>=64) stage tile 0
        if (tid >= 64) {
            int st = tid - 64;                          // 0..191
            for (int f = st; f < TILE / 4; f += 192) {
                float4 v4 = ((const float4*)xr)[f];
                #pragma unroll
                for (int q = 0; q < 4; q++) {
                    int g = f * 4 + q;
                    float v = (&v4.x)[q];
                    if (mode) { float c = __fsub_rn(v, mean); v = __fmul_rn(c, c); }
                    buf[0][g & 7][g >> 3] = v;
                }
            }
        }
        __syncthreads();

        float p = 0.0f;
        for (int t = 0; t < NT; t++) {
            if (tid < VF) {
                // pure chain wave: exact XLA lane order; A/B 64-float pipeline.
                const f32x4* srcl = (const f32x4*)&buf[t & 1][tid][0];
                f32x4 A[16], B[16];
                #pragma unroll
                for (int j = 0; j < 16; j++) A[j] = srcl[j];
                #pragma unroll
                for (int c = 0; c < NCH; c++) {
                    f32x4* cur = (c & 1) ? B : A;     // static after unroll
                    f32x4* nxt = (c & 1) ? A : B;
                    if (c + 1 < NCH) {
                        #pragma unroll
                        for (int j = 0; j < 16; j++) nxt[j] = srcl[(c + 1) * 16 + j];
                    }
                    // pin: next-chunk loads are issued above, adds stay below
                    asm volatile("" ::: "memory");
                    #pragma unroll
                    for (int j = 0; j < 16; j++) {
                        p = __fadd_rn(p, cur[j].x); p = __fadd_rn(p, cur[j].y);
                        p = __fadd_rn(p, cur[j].z); p = __fadd_rn(p, cur[j].w);
                    }
                }
            } else if (tid >= 64 && t + 1 < NT) {
                // stagers: load + transpose next tile into the other buffer
                int st = tid - 64;
                const float* src = xr + (size_t)(t + 1) * TILE;
                for (int f = st; f < TILE / 4; f += 192) {
                    float4 v4 = ((const float4*)src)[f];
                    #pragma unroll
                    for (int q = 0; q < 4; q++) {
                        int g = f * 4 + q;
                        float v = (&v4.x)[q];
                        if (mode) { float c = __fsub_rn(v, mean); v = __fmul_rn(c, c); }
                        buf[(t + 1) & 1][g & 7][g >> 3] = v;
                    }
                }
            }
            __syncthreads();
        }
        if (tid < VF) partial[tid] = p;
        __syncthreads();
        if (tid == 0) {
            float tr[VF];
            for (int j = 0; j < VF; j++) tr[j] = partial[j];
            for (int w = VF / 2; w >= 1; w >>= 1)
                for (int j = 0; j < w; j++) tr[j] = __fadd_rn(tr[j], tr[j + w]);
            float S = tr[0];
            if (mode == 0) {
                mean_sh = __fdiv_rn(S, 262144.0f);
            } else {
                float var = __fdiv_rn(S, 262143.0f);
                float sd  = __fsqrt_rn(var);
                beta_out[row] = __fdiv_rn(sd, (float)(0.1 + 1e-6));
            }
        }
        __syncthreads();
    }
}

// ================= exact MSB radix-select (4 x 8-bit digits) =================
__device__ const unsigned pass_himask[4] = {0x00000000u, 0xFF000000u, 0xFFFF0000u, 0xFFFFFF00u};
__device__ const int      pass_shift[4]  = {24, 16, 8, 0};

// pass 0: vectorized key build (x4 + g4), acts cache write, zero-skip hist
__global__ void k_hist0(const float* __restrict__ x, const float* __restrict__ u,
                        const float* __restrict__ g, const float* __restrict__ beta,
                        float* __restrict__ acts_out, unsigned* __restrict__ cnt) {
    __shared__ unsigned lh[256];
    int row = blockIdx.x >> 4, blk = blockIdx.x & 15;
    lh[threadIdx.x] = 0;
    __syncthreads();
    float bt = beta[row];
    size_t base4 = ((size_t)row * NPB + (size_t)blk * (NPB / 16)) / 4;
    const float4* x4 = (const float4*)x;
    const float4* g4 = (const float4*)g;
    float4* a4 = (float4*)acts_out;
    unsigned zc = 0;
    for (int i = threadIdx.x; i < NPB / 16 / 4; i += 256) {
        float4 xx = x4[base4 + i];
        unsigned k[4];
        if (g) {
            float4 gg = g4[base4 + i];
            k[0] = key_from_g(xx.x, gg.x, bt); k[1] = key_from_g(xx.y, gg.y, bt);
            k[2] = key_from_g(xx.z, gg.z, bt); k[3] = key_from_g(xx.w, gg.w, bt);
        } else {
            const float4 uu = ((const float4*)u)[base4 + i];
            k[0] = act_key(xx.x, uu.x, bt); k[1] = act_key(xx.y, uu.y, bt);
            k[2] = act_key(xx.z, uu.z, bt); k[3] = act_key(xx.w, uu.w, bt);
        }
        if (acts_out) {
            float4 av;
            av.x = __uint_as_float(k[0]); av.y = __uint_as_float(k[1]);
            av.z = __uint_as_float(k[2]); av.w = __uint_as_float(k[3]);
            a4[base4 + i] = av;
        }
        #pragma unroll
        for (int q = 0; q < 4; q++) {
            if (k[q]) atomicAdd(&lh[k[q] >> 24], 1u);
            else      zc++;
        }
    }
    if (zc) atomicAdd(&lh[0], zc);
    __syncthreads();
    if (lh[threadIdx.x])
        atomicAdd(&cnt[(size_t)row * 256 + threadIdx.x], lh[threadIdx.x]);
}

// passes 1-3: vectorized acts read, conditional (rare) atomics
__global__ void k_histN(const float* __restrict__ x, const float* __restrict__ u,
                        const float* __restrict__ beta, const float* __restrict__ acts_in,
                        unsigned* __restrict__ cnt, const unsigned* __restrict__ prefix, int p) {
    __shared__ unsigned lh[256];
    int row = blockIdx.x >> 4, blk = blockIdx.x & 15;
    lh[threadIdx.x] = 0;
    __syncthreads();
    unsigned pfx = prefix[row];
    unsigned hm  = pass_himask[p];
    int sh = pass_shift[p];
    size_t base = (size_t)row * NPB + (size_t)blk * (NPB / 16);
    if (acts_in) {
        const float4* a4 = (const float4*)(acts_in + base);
        for (int i = threadIdx.x; i < NPB / 16 / 4; i += 256) {
            float4 av = a4[i];
            #pragma unroll
            for (int q = 0; q < 4; q++) {
                unsigned key = __float_as_uint((&av.x)[q]);
                if ((key & hm) == pfx)
                    atomicAdd(&lh[(key >> sh) & 255u], 1u);
            }
        }
    } else {
        float bt = beta[row];
        for (int i = threadIdx.x; i < NPB / 16; i += 256) {
            unsigned key = act_key(x[base + i], u[base + i], bt);
            if ((key & hm) == pfx)
                atomicAdd(&lh[(key >> sh) & 255u], 1u);
        }
    }
    __syncthreads();
    if (lh[threadIdx.x])
        atomicAdd(&cnt[(size_t)row * 256 + threadIdx.x], lh[threadIdx.x]);
}

__global__ void k_sel(const unsigned* __restrict__ cnt, unsigned* prefix, unsigned* rank, int p) {
    if (threadIdx.x != 0) return;
    int row = blockIdx.x;
    unsigned r   = (p == 0) ? K_SEL : rank[row];
    unsigned pfx = (p == 0) ? 0u : prefix[row];
    const unsigned* h = cnt + (size_t)row * 256;
    int sh = pass_shift[p];
    unsigned c = 0;
    for (int v = 255; v >= 0; v--) {
        unsigned hv = h[v];
        if (c + hv >= r) {
            prefix[row] = pfx | ((unsigned)v << sh);
            rank[row]   = r - c;
            return;
        }
        c += hv;
    }
}

__global__ void k_write(const float* __restrict__ x, const float* __restrict__ u,
                        const float* __restrict__ beta, const float* __restrict__ acts_in,
                        const unsigned* __restrict__ prefix, float* __restrict__ out) {
    size_t e4 = (size_t)blockIdx.x * 256 + threadIdx.x;     // float4 index
    int row = (int)(e4 >> (LOG2_NPB - 2));
    unsigned kb = prefix[row];
    unsigned k[4];
    if (acts_in) {
        float4 av = ((const float4*)acts_in)[e4];
        #pragma unroll
        for (int q = 0; q < 4; q++) k[q] = __float_as_uint((&av.x)[q]);
    } else {
        float bt = beta[row];
        const float4 xx = ((const float4*)x)[e4];
        const float4 uu = ((const float4*)u)[e4];
        k[0] = act_key(xx.x, uu.x, bt); k[1] = act_key(xx.y, uu.y, bt);
        k[2] = act_key(xx.z, uu.z, bt); k[3] = act_key(xx.w, uu.w, bt);
    }
    float4 sp, mk;
    #pragma unroll
    for (int q = 0; q < 4; q++) {
        bool m = (k[q] >= kb);
        (&sp.x)[q] = m ? __uint_as_float(k[q]) : 0.0f;
        (&mk.x)[q] = m ? 1.0f : 0.0f;
    }
    ((float4*)out)[e4] = sp;
    ((float4*)(out + NTOT))[e4] = mk;
}

extern "C" void kernel_launch(void* const* d_in, const int* in_sizes, int n_in,
                              void* d_out, int out_size, void* d_ws, size_t ws_size,
                              hipStream_t stream) {
    const float* x = (const float*)d_in[0];
    const float* u = (const float*)d_in[1];
    float* out = (float*)d_out;
    char* ws = (char*)d_ws;

    float*    beta    = (float*)(ws + OFF_BETA);
    unsigned* cnt     = (unsigned*)(ws + OFF_CNT);
    unsigned* prefix  = (unsigned*)(ws + OFF_PFX);
    unsigned* rank    = (unsigned*)(ws + OFF_RANK);
    float*    acts    = (ws_size >= WS_NEED_ACTS) ? (float*)(ws + OFF_ACTS) : nullptr;
    float*    g       = (ws_size >= WS_NEED_G)    ? (float*)(ws + OFF_G)    : nullptr;

    hipMemsetAsync(ws + OFF_CNT, 0, 131328, stream);  // cnt + pfx + rank

    k_std<<<NROWS + GBLK, 256, 0, stream>>>(x, u, beta, g);

    k_hist0<<<NROWS * 16, 256, 0, stream>>>(x, u, g, beta, acts, cnt);
    k_sel  <<<NROWS, 64, 0, stream>>>(cnt, prefix, rank, 0);
    for (int p = 1; p < 4; p++) {
        k_histN<<<NROWS * 16, 256, 0, stream>>>(x, u, beta, acts,
                                                cnt + (size_t)p * NROWS * 256, prefix, p);
        k_sel  <<<NROWS, 64, 0, stream>>>(cnt + (size_t)p * NROWS * 256, prefix, rank, p);
    }

    k_write<<<NTOT / 4 / 256, 256, 0, stream>>>(x, u, beta, acts, prefix, out);
}

// Round 14
// 349.572 us; speedup vs baseline: 6.4573x; 1.0057x over previous
//
#include <hip/hip_runtime.h>

#define NROWS 32
#define NPB   262144
#define LOG2_NPB 18
#define K_SEL 13107u
#define NTOT  (NROWS * NPB)
#define VF 8

// k_std tiling
#define TILE   8192              // floats per staged tile (32 KB)
#define NT     (NPB / TILE)      // 32 tiles
#define CPL    (TILE / VF)       // 1024 chain floats per tile per lane
#define LROW   1028              // padded LDS row; 1028*4 = 4112 B, 16B-aligned
#define GBLK   224               // g-precompute blocks appended to k_std grid

typedef __attribute__((ext_vector_type(4))) float f32x4;

// ---------- ws layout (byte offsets) ----------
#define OFF_BETA  4224     // float[32]
#define OFF_CNT   4352     // uint[4][32][256] = 131072 (zeroed)
#define OFF_PFX   135424   // uint[32] (zeroed)
#define OFF_RANK  135552   // uint[32] (zeroed)
#define OFF_ACTS  1048576                    // float[NTOT] acts-key cache
#define OFF_G     (OFF_ACTS + (size_t)NTOT*4) // float[NTOT] g cache
#define WS_NEED_ACTS (OFF_ACTS + (size_t)NTOT * 4)
#define WS_NEED_G    (OFF_G    + (size_t)NTOT * 4)

// ======== XLA:CPU f32 log twin (GenerateVF32Log / Eigen plog, Cephes) ========
// Unfused mul+add at every MulAdd. FROZEN: bits validated round 8.
__device__ __forceinline__ float xla_logf(float xf) {
    unsigned b = __float_as_uint(xf);
    float e = (float)(int)((b >> 23) - 126u);
    float m = __uint_as_float((b & 0x007FFFFFu) | 0x3F000000u);   // [0.5,1)
    bool mk = m < 0.707106781186547524f;
    float tmp = mk ? m : 0.0f;
    if (mk) e = __fsub_rn(e, 1.0f);
    float x = __fadd_rn(__fsub_rn(m, 1.0f), tmp);
    float z  = __fmul_rn(x, x);
    float x3 = __fmul_rn(z, x);
    float y  = __fadd_rn(__fmul_rn( 7.0376836292e-2f, x), -1.1514610310e-1f);
    float y1 = __fadd_rn(__fmul_rn(-1.2420140846e-1f, x),  1.4249322787e-1f);
    float y2 = __fadd_rn(__fmul_rn( 2.0000714765e-1f, x), -2.4999993993e-1f);
    y  = __fadd_rn(__fmul_rn(y,  x),  1.1676998740e-1f);
    y1 = __fadd_rn(__fmul_rn(y1, x), -1.6668057665e-1f);
    y2 = __fadd_rn(__fmul_rn(y2, x),  3.3333331174e-1f);
    y  = __fadd_rn(__fmul_rn(y, x3), y1);
    y  = __fadd_rn(__fmul_rn(y, x3), y2);
    y  = __fmul_rn(y, x3);
    y  = __fadd_rn(__fmul_rn(e, -2.12194440e-4f), y);
    y  = __fsub_rn(y, __fmul_rn(z, 0.5f));
    x  = __fadd_rn(x, y);
    x  = __fadd_rn(__fmul_rn(e, 0.693359375f), x);
    return x;
}

__device__ __forceinline__ float g_of(float uf) {
    float i1 = xla_logf(uf);
    float i3 = xla_logf(-i1);
    return -i3;
}

__device__ __forceinline__ unsigned key_from_g(float xf, float gf, float bt) {
    float a = fmaxf(__fadd_rn(xf, __fmul_rn(bt, gf)), 0.0f);
    unsigned key = __float_as_uint(a);
    if (key == 0x80000000u) key = 0u;
    return key;
}

__device__ __forceinline__ unsigned act_key(float xf, float uf, float bt) {
    return key_from_g(xf, g_of(uf), bt);
}

// ---- inline-asm chain plumbing ----
// LDS flat->offset: AMDGPU lowers flat->local addrspacecast as a 32-bit
// truncate (shared aperture base has zero low bits), so truncation = offset.
__device__ __forceinline__ unsigned lds_addr(const void* p) {
    return (unsigned)(size_t)p;
}

// issue 8 ds_read_b128 (32 floats) from ADDR with literal offsets 0..112
#define ISSUE8(r0,r1,r2,r3,r4,r5,r6,r7, ADDR)                                \
    asm volatile("ds_read_b128 %0, %8 offset:0\n\t"                          \
                 "ds_read_b128 %1, %8 offset:16\n\t"                         \
                 "ds_read_b128 %2, %8 offset:32\n\t"                         \
                 "ds_read_b128 %3, %8 offset:48\n\t"                         \
                 "ds_read_b128 %4, %8 offset:64\n\t"                         \
                 "ds_read_b128 %5, %8 offset:80\n\t"                         \
                 "ds_read_b128 %6, %8 offset:96\n\t"                         \
                 "ds_read_b128 %7, %8 offset:112"                            \
                 : "=&v"(r0), "=&v"(r1), "=&v"(r2), "=&v"(r3),               \
                   "=&v"(r4), "=&v"(r5), "=&v"(r6), "=&v"(r7)                \
                 : "v"(ADDR) : "memory")

// wait: 8 newer DS reads in flight, older 8 certified landed (in-order DS)
#define WAIT8  do { asm volatile("s_waitcnt lgkmcnt(8)" ::: "memory");       \
                    __builtin_amdgcn_sched_barrier(0); } while (0)
#define WAIT0  do { asm volatile("s_waitcnt lgkmcnt(0)" ::: "memory");       \
                    __builtin_amdgcn_sched_barrier(0); } while (0)

// 32 sequential __fadd_rn in ascending-address (XLA lane) order
#define ADD4(r)  do { p = __fadd_rn(p, r.x); p = __fadd_rn(p, r.y);          \
                      p = __fadd_rn(p, r.z); p = __fadd_rn(p, r.w); } while (0)
#define ADD32(r0,r1,r2,r3,r4,r5,r6,r7)                                       \
    do { ADD4(r0); ADD4(r1); ADD4(r2); ADD4(r3);                             \
         ADD4(r4); ADD4(r5); ADD4(r6); ADD4(r7); } while (0)

// ======== k_std: XLA VF=8 reduce twin + fused g-precompute ========
// Blocks 0..31: one per row. Wave 0 lanes 0-7 run the exact sequential
// __fadd_rn chains with an inline-asm ds_read_b128 + counted-lgkmcnt
// pipeline (compiler-proof); threads 64-255 stage+transpose tiles into
// double-buffered LDS. Blocks 32+: g = -log(-log u) precompute (overlaps).
__global__ __launch_bounds__(256, 1) void k_std(const float* __restrict__ x,
                                                const float* __restrict__ u,
                                                float* __restrict__ beta_out,
                                                float* __restrict__ g_out) {
    __shared__ __align__(16) float buf[2][VF][LROW];   // 65792 B
    __shared__ float partial[VF];
    __shared__ float mean_sh;
    int tid = threadIdx.x;

    if (blockIdx.x >= NROWS) {                 // ---- g-precompute blocks ----
        if (!g_out) return;
        const float4* u4 = (const float4*)u;
        float4* g4 = (float4*)g_out;
        int idx = (blockIdx.x - NROWS) * 256 + tid;
        int stride = GBLK * 256;
        for (int i = idx; i < NTOT / 4; i += stride) {
            float4 uu = u4[i];
            float4 gg;
            gg.x = g_of(uu.x); gg.y = g_of(uu.y);
            gg.z = g_of(uu.z); gg.w = g_of(uu.w);
            g4[i] = gg;
        }
        return;
    }

    int row = blockIdx.x;
    const float* xr = x + (size_t)row * NPB;

    for (int mode = 0; mode < 2; mode++) {
        float mean = (mode == 1) ? mean_sh : 0.0f;
        // prologue: stagers (tid>=64) stage tile 0
        if (tid >= 64) {
            int st = tid - 64;                          // 0..191
            for (int f = st; f < TILE / 4; f += 192) {
                float4 v4 = ((const float4*)xr)[f];
                #pragma unroll
                for (int q = 0; q < 4; q++) {
                    int g = f * 4 + q;
                    float v = (&v4.x)[q];
                    if (mode) { float c = __fsub_rn(v, mean); v = __fmul_rn(c, c); }
                    buf[0][g & 7][g >> 3] = v;
                }
            }
        }
        __syncthreads();

        float p = 0.0f;
        for (int t = 0; t < NT; t++) {
            if (tid < VF) {
                unsigned base = lds_addr(&buf[t & 1][tid][0]);
                f32x4 A0, A1, A2, A3, A4, A5, A6, A7;
                f32x4 B0, B1, B2, B3, B4, B5, B6, B7;
                ISSUE8(A0, A1, A2, A3, A4, A5, A6, A7, base);      // chunk 0
                unsigned ad = base + 128;
                #pragma unroll 1
                for (int c = 0; c < 30; c += 2) {
                    ISSUE8(B0, B1, B2, B3, B4, B5, B6, B7, ad);    // chunk c+1
                    WAIT8;                                          // A landed
                    ADD32(A0, A1, A2, A3, A4, A5, A6, A7);
                    ISSUE8(A0, A1, A2, A3, A4, A5, A6, A7, ad + 128); // c+2
                    WAIT8;                                          // B landed
                    ADD32(B0, B1, B2, B3, B4, B5, B6, B7);
                    ad += 256;
                }
                ISSUE8(B0, B1, B2, B3, B4, B5, B6, B7, ad);        // chunk 31
                WAIT8;                                              // A30 landed
                ADD32(A0, A1, A2, A3, A4, A5, A6, A7);
                WAIT0;                                              // B31 landed
                ADD32(B0, B1, B2, B3, B4, B5, B6, B7);
            } else if (tid >= 64 && t + 1 < NT) {
                // stagers: load + transpose next tile into the other buffer
                int st = tid - 64;
                const float* src = xr + (size_t)(t + 1) * TILE;
                for (int f = st; f < TILE / 4; f += 192) {
                    float4 v4 = ((const float4*)src)[f];
                    #pragma unroll
                    for (int q = 0; q < 4; q++) {
                        int g = f * 4 + q;
                        float v = (&v4.x)[q];
                        if (mode) { float c = __fsub_rn(v, mean); v = __fmul_rn(c, c); }
                        buf[(t + 1) & 1][g & 7][g >> 3] = v;
                    }
                }
            }
            __syncthreads();
        }
        if (tid < VF) partial[tid] = p;
        __syncthreads();
        if (tid == 0) {
            float tr[VF];
            for (int j = 0; j < VF; j++) tr[j] = partial[j];
            for (int w = VF / 2; w >= 1; w >>= 1)
                for (int j = 0; j < w; j++) tr[j] = __fadd_rn(tr[j], tr[j + w]);
            float S = tr[0];
            if (mode == 0) {
                mean_sh = __fdiv_rn(S, 262144.0f);
            } else {
                float var = __fdiv_rn(S, 262143.0f);
                float sd  = __fsqrt_rn(var);
                beta_out[row] = __fdiv_rn(sd, (float)(0.1 + 1e-6));
            }
        }
        __syncthreads();
    }
}

// ================= exact MSB radix-select (4 x 8-bit digits) =================
__device__ const unsigned pass_himask[4] = {0x00000000u, 0xFF000000u, 0xFFFF0000u, 0xFFFFFF00u};
__device__ const int      pass_shift[4]  = {24, 16, 8, 0};

// pass 0: vectorized key build (x4 + g4), acts cache write, zero-skip hist
__global__ void k_hist0(const float* __restrict__ x, const float* __restrict__ u,
                        const float* __restrict__ g, const float* __restrict__ beta,
                        float* __restrict__ acts_out, unsigned* __restrict__ cnt) {
    __shared__ unsigned lh[256];
    int row = blockIdx.x >> 4, blk = blockIdx.x & 15;
    lh[threadIdx.x] = 0;
    __syncthreads();
    float bt = beta[row];
    size_t base4 = ((size_t)row * NPB + (size_t)blk * (NPB / 16)) / 4;
    const float4* x4 = (const float4*)x;
    const float4* g4 = (const float4*)g;
    float4* a4 = (float4*)acts_out;
    unsigned zc = 0;
    for (int i = threadIdx.x; i < NPB / 16 / 4; i += 256) {
        float4 xx = x4[base4 + i];
        unsigned k[4];
        if (g) {
            float4 gg = g4[base4 + i];
            k[0] = key_from_g(xx.x, gg.x, bt); k[1] = key_from_g(xx.y, gg.y, bt);
            k[2] = key_from_g(xx.z, gg.z, bt); k[3] = key_from_g(xx.w, gg.w, bt);
        } else {
            const float4 uu = ((const float4*)u)[base4 + i];
            k[0] = act_key(xx.x, uu.x, bt); k[1] = act_key(xx.y, uu.y, bt);
            k[2] = act_key(xx.z, uu.z, bt); k[3] = act_key(xx.w, uu.w, bt);
        }
        if (acts_out) {
            float4 av;
            av.x = __uint_as_float(k[0]); av.y = __uint_as_float(k[1]);
            av.z = __uint_as_float(k[2]); av.w = __uint_as_float(k[3]);
            a4[base4 + i] = av;
        }
        #pragma unroll
        for (int q = 0; q < 4; q++) {
            if (k[q]) atomicAdd(&lh[k[q] >> 24], 1u);
            else      zc++;
        }
    }
    if (zc) atomicAdd(&lh[0], zc);
    __syncthreads();
    if (lh[threadIdx.x])
        atomicAdd(&cnt[(size_t)row * 256 + threadIdx.x], lh[threadIdx.x]);
}

// passes 1-3: vectorized acts read, conditional (rare) atomics
__global__ void k_histN(const float* __restrict__ x, const float* __restrict__ u,
                        const float* __restrict__ beta, const float* __restrict__ acts_in,
                        unsigned* __restrict__ cnt, const unsigned* __restrict__ prefix, int p) {
    __shared__ unsigned lh[256];
    int row = blockIdx.x >> 4, blk = blockIdx.x & 15;
    lh[threadIdx.x] = 0;
    __syncthreads();
    unsigned pfx = prefix[row];
    unsigned hm  = pass_himask[p];
    int sh = pass_shift[p];
    size_t base = (size_t)row * NPB + (size_t)blk * (NPB / 16);
    if (acts_in) {
        const float4* a4 = (const float4*)(acts_in + base);
        for (int i = threadIdx.x; i < NPB / 16 / 4; i += 256) {
            float4 av = a4[i];
            #pragma unroll
            for (int q = 0; q < 4; q++) {
                unsigned key = __float_as_uint((&av.x)[q]);
                if ((key & hm) == pfx)
                    atomicAdd(&lh[(key >> sh) & 255u], 1u);
            }
        }
    } else {
        float bt = beta[row];
        for (int i = threadIdx.x; i < NPB / 16; i += 256) {
            unsigned key = act_key(x[base + i], u[base + i], bt);
            if ((key & hm) == pfx)
                atomicAdd(&lh[(key >> sh) & 255u], 1u);
        }
    }
    __syncthreads();
    if (lh[threadIdx.x])
        atomicAdd(&cnt[(size_t)row * 256 + threadIdx.x], lh[threadIdx.x]);
}

__global__ void k_sel(const unsigned* __restrict__ cnt, unsigned* prefix, unsigned* rank, int p) {
    if (threadIdx.x != 0) return;
    int row = blockIdx.x;
    unsigned r   = (p == 0) ? K_SEL : rank[row];
    unsigned pfx = (p == 0) ? 0u : prefix[row];
    const unsigned* h = cnt + (size_t)row * 256;
    int sh = pass_shift[p];
    unsigned c = 0;
    for (int v = 255; v >= 0; v--) {
        unsigned hv = h[v];
        if (c + hv >= r) {
            prefix[row] = pfx | ((unsigned)v << sh);
            rank[row]   = r - c;
            return;
        }
        c += hv;
    }
}

__global__ void k_write(const float* __restrict__ x, const float* __restrict__ u,
                        const float* __restrict__ beta, const float* __restrict__ acts_in,
                        const unsigned* __restrict__ prefix, float* __restrict__ out) {
    size_t e4 = (size_t)blockIdx.x * 256 + threadIdx.x;     // float4 index
    int row = (int)(e4 >> (LOG2_NPB - 2));
    unsigned kb = prefix[row];
    unsigned k[4];
    if (acts_in) {
        float4 av = ((const float4*)acts_in)[e4];
        #pragma unroll
        for (int q = 0; q < 4; q++) k[q] = __float_as_uint((&av.x)[q]);
    } else {
        float bt = beta[row];
        const float4 xx = ((const float4*)x)[e4];
        const float4 uu = ((const float4*)u)[e4];
        k[0] = act_key(xx.x, uu.x, bt); k[1] = act_key(xx.y, uu.y, bt);
        k[2] = act_key(xx.z, uu.z, bt); k[3] = act_key(xx.w, uu.w, bt);
    }
    float4 sp, mk;
    #pragma unroll
    for (int q = 0; q < 4; q++) {
        bool m = (k[q] >= kb);
        (&sp.x)[q] = m ? __uint_as_float(k[q]) : 0.0f;
        (&mk.x)[q] = m ? 1.0f : 0.0f;
    }
    ((float4*)out)[e4] = sp;
    ((float4*)(out + NTOT))[e4] = mk;
}

extern "C" void kernel_launch(void* const* d_in, const int* in_sizes, int n_in,
                              void* d_out, int out_size, void* d_ws, size_t ws_size,
                              hipStream_t stream) {
    const float* x = (const float*)d_in[0];
    const float* u = (const float*)d_in[1];
    float* out = (float*)d_out;
    char* ws = (char*)d_ws;

    float*    beta    = (float*)(ws + OFF_BETA);
    unsigned* cnt     = (unsigned*)(ws + OFF_CNT);
    unsigned* prefix  = (unsigned*)(ws + OFF_PFX);
    unsigned* rank    = (unsigned*)(ws + OFF_RANK);
    float*    acts    = (ws_size >= WS_NEED_ACTS) ? (float*)(ws + OFF_ACTS) : nullptr;
    float*    g       = (ws_size >= WS_NEED_G)    ? (float*)(ws + OFF_G)    : nullptr;

    hipMemsetAsync(ws + OFF_CNT, 0, 131328, stream);  // cnt + pfx + rank

    k_std<<<NROWS + GBLK, 256, 0, stream>>>(x, u, beta, g);

    k_hist0<<<NROWS * 16, 256, 0, stream>>>(x, u, g, beta, acts, cnt);
    k_sel  <<<NROWS, 64, 0, stream>>>(cnt, prefix, rank, 0);
    for (int p = 1; p < 4; p++) {
        k_histN<<<NROWS * 16, 256, 0, stream>>>(x, u, beta, acts,
                                                cnt + (size_t)p * NROWS * 256, prefix, p);
        k_sel  <<<NROWS, 64, 0, stream>>>(cnt + (size_t)p * NROWS * 256, prefix, rank, p);
    }

    k_write<<<NTOT / 4 / 256, 256, 0, stream>>>(x, u, beta, acts, prefix, out);
}

// Round 15
// 342.650 us; speedup vs baseline: 6.5877x; 1.0202x over previous
//
#include <hip/hip_runtime.h>

#define NROWS 32
#define NPB   262144
#define LOG2_NPB 18
#define K_SEL 13107u
#define NTOT  (NROWS * NPB)
#define VF 8

// k_std tiling
#define TILE   8192              // floats per staged tile (32 KB)
#define NT     (NPB / TILE)      // 32 tiles
#define LROW   1028              // padded LDS row; 1028*4 = 4112 B, 16B-aligned
#define GBLK   224               // g-precompute blocks appended to k_std grid

typedef __attribute__((ext_vector_type(4))) float f32x4;

// ---------- ws layout (byte offsets) ----------
#define OFF_BETA  4224     // float[32]
#define OFF_CNT   4352     // uint[4][32][256] = 131072 (zeroed)
#define OFF_PFX   135424   // uint[32] (zeroed)
#define OFF_RANK  135552   // uint[32] (zeroed)
#define OFF_ACTS  1048576                    // float[NTOT] acts-key cache
#define OFF_G     (OFF_ACTS + (size_t)NTOT*4) // float[NTOT] g cache
#define WS_NEED_ACTS (OFF_ACTS + (size_t)NTOT * 4)
#define WS_NEED_G    (OFF_G    + (size_t)NTOT * 4)

// ======== XLA:CPU f32 log twin (GenerateVF32Log / Eigen plog, Cephes) ========
// Unfused mul+add at every MulAdd. FROZEN: bits validated round 8.
__device__ __forceinline__ float xla_logf(float xf) {
    unsigned b = __float_as_uint(xf);
    float e = (float)(int)((b >> 23) - 126u);
    float m = __uint_as_float((b & 0x007FFFFFu) | 0x3F000000u);   // [0.5,1)
    bool mk = m < 0.707106781186547524f;
    float tmp = mk ? m : 0.0f;
    if (mk) e = __fsub_rn(e, 1.0f);
    float x = __fadd_rn(__fsub_rn(m, 1.0f), tmp);
    float z  = __fmul_rn(x, x);
    float x3 = __fmul_rn(z, x);
    float y  = __fadd_rn(__fmul_rn( 7.0376836292e-2f, x), -1.1514610310e-1f);
    float y1 = __fadd_rn(__fmul_rn(-1.2420140846e-1f, x),  1.4249322787e-1f);
    float y2 = __fadd_rn(__fmul_rn( 2.0000714765e-1f, x), -2.4999993993e-1f);
    y  = __fadd_rn(__fmul_rn(y,  x),  1.1676998740e-1f);
    y1 = __fadd_rn(__fmul_rn(y1, x), -1.6668057665e-1f);
    y2 = __fadd_rn(__fmul_rn(y2, x),  3.3333331174e-1f);
    y  = __fadd_rn(__fmul_rn(y, x3), y1);
    y  = __fadd_rn(__fmul_rn(y, x3), y2);
    y  = __fmul_rn(y, x3);
    y  = __fadd_rn(__fmul_rn(e, -2.12194440e-4f), y);
    y  = __fsub_rn(y, __fmul_rn(z, 0.5f));
    x  = __fadd_rn(x, y);
    x  = __fadd_rn(__fmul_rn(e, 0.693359375f), x);
    return x;
}

__device__ __forceinline__ float g_of(float uf) {
    float i1 = xla_logf(uf);
    float i3 = xla_logf(-i1);
    return -i3;
}

__device__ __forceinline__ unsigned key_from_g(float xf, float gf, float bt) {
    float a = fmaxf(__fadd_rn(xf, __fmul_rn(bt, gf)), 0.0f);
    unsigned key = __float_as_uint(a);
    if (key == 0x80000000u) key = 0u;
    return key;
}

__device__ __forceinline__ unsigned act_key(float xf, float uf, float bt) {
    return key_from_g(xf, g_of(uf), bt);
}

// ---- inline-asm chain plumbing ----
__device__ __forceinline__ unsigned lds_addr(const void* p) {
    return (unsigned)(size_t)p;    // LDS aperture: truncation = LDS offset
}

// issue 8 ds_read_b128 (32 floats of one lane-row) from ADDR
#define ISSUE8(r0,r1,r2,r3,r4,r5,r6,r7, ADDR)                                \
    asm volatile("ds_read_b128 %0, %8 offset:0\n\t"                          \
                 "ds_read_b128 %1, %8 offset:16\n\t"                         \
                 "ds_read_b128 %2, %8 offset:32\n\t"                         \
                 "ds_read_b128 %3, %8 offset:48\n\t"                         \
                 "ds_read_b128 %4, %8 offset:64\n\t"                         \
                 "ds_read_b128 %5, %8 offset:80\n\t"                         \
                 "ds_read_b128 %6, %8 offset:96\n\t"                         \
                 "ds_read_b128 %7, %8 offset:112"                            \
                 : "=&v"(r0), "=&v"(r1), "=&v"(r2), "=&v"(r3),               \
                   "=&v"(r4), "=&v"(r5), "=&v"(r6), "=&v"(r7)                \
                 : "v"(ADDR) : "memory")

// counted waits (lgkmcnt is a 4-bit field: max literal 15); DS is in-order,
// so wait-N certifies all but the newest N DS ops have completed.
#define WAIT15 do { asm volatile("s_waitcnt lgkmcnt(15)" ::: "memory");      \
                    __builtin_amdgcn_sched_barrier(0); } while (0)
#define WAIT8  do { asm volatile("s_waitcnt lgkmcnt(8)" ::: "memory");       \
                    __builtin_amdgcn_sched_barrier(0); } while (0)
#define WAIT0  do { asm volatile("s_waitcnt lgkmcnt(0)" ::: "memory");       \
                    __builtin_amdgcn_sched_barrier(0); } while (0)

// 32 sequential __fadd_rn in ascending-address (XLA lane) order
#define ADD4(r)  do { p = __fadd_rn(p, r.x); p = __fadd_rn(p, r.y);          \
                      p = __fadd_rn(p, r.z); p = __fadd_rn(p, r.w); } while (0)
#define ADD32(r0,r1,r2,r3,r4,r5,r6,r7)                                       \
    do { ADD4(r0); ADD4(r1); ADD4(r2); ADD4(r3);                             \
         ADD4(r4); ADD4(r5); ADD4(r6); ADD4(r7); } while (0)

#define ISSUE_A ISSUE8(A0,A1,A2,A3,A4,A5,A6,A7
#define ISSUE_B ISSUE8(B0,B1,B2,B3,B4,B5,B6,B7
#define ISSUE_C ISSUE8(C0,C1,C2,C3,C4,C5,C6,C7
#define ADD_A   ADD32(A0,A1,A2,A3,A4,A5,A6,A7)
#define ADD_B   ADD32(B0,B1,B2,B3,B4,B5,B6,B7)
#define ADD_C   ADD32(C0,C1,C2,C3,C4,C5,C6,C7)

// ======== k_std: XLA VF=8 reduce twin + fused g-precompute ========
// Blocks 0..31: one per row. Wave 0 lanes 0-7 run the exact sequential
// __fadd_rn chains with a DEPTH-3 inline-asm ds_read_b128 pipeline
// (~290 cyc issue-to-wait slack, vs depth-2's ~130 which stalled);
// threads 64-255 stage+transpose tiles into double-buffered LDS.
// Blocks 32+: g = -log(-log u) precompute (beta-independent, overlaps).
__global__ __launch_bounds__(256, 1) void k_std(const float* __restrict__ x,
                                                const float* __restrict__ u,
                                                float* __restrict__ beta_out,
                                                float* __restrict__ g_out) {
    __shared__ __align__(16) float buf[2][VF][LROW];   // 65792 B
    __shared__ float partial[VF];
    __shared__ float mean_sh;
    int tid = threadIdx.x;

    if (blockIdx.x >= NROWS) {                 // ---- g-precompute blocks ----
        if (!g_out) return;
        const float4* u4 = (const float4*)u;
        float4* g4 = (float4*)g_out;
        int idx = (blockIdx.x - NROWS) * 256 + tid;
        int stride = GBLK * 256;
        for (int i = idx; i < NTOT / 4; i += stride) {
            float4 uu = u4[i];
            float4 gg;
            gg.x = g_of(uu.x); gg.y = g_of(uu.y);
            gg.z = g_of(uu.z); gg.w = g_of(uu.w);
            g4[i] = gg;
        }
        return;
    }

    int row = blockIdx.x;
    const float* xr = x + (size_t)row * NPB;

    for (int mode = 0; mode < 2; mode++) {
        float mean = (mode == 1) ? mean_sh : 0.0f;
        // prologue: stagers (tid>=64) stage tile 0
        if (tid >= 64) {
            int st = tid - 64;                          // 0..191
            for (int f = st; f < TILE / 4; f += 192) {
                float4 v4 = ((const float4*)xr)[f];
                #pragma unroll
                for (int q = 0; q < 4; q++) {
                    int g = f * 4 + q;
                    float v = (&v4.x)[q];
                    if (mode) { float c = __fsub_rn(v, mean); v = __fmul_rn(c, c); }
                    buf[0][g & 7][g >> 3] = v;
                }
            }
        }
        __syncthreads();

        float p = 0.0f;
        for (int t = 0; t < NT; t++) {
            if (tid < VF) {
                // depth-3 pipeline over 32 chunks of 32 floats
                unsigned base = lds_addr(&buf[t & 1][tid][0]);
                f32x4 A0, A1, A2, A3, A4, A5, A6, A7;
                f32x4 B0, B1, B2, B3, B4, B5, B6, B7;
                f32x4 C0, C1, C2, C3, C4, C5, C6, C7;
                ISSUE_A, base);            // chunk 0
                ISSUE_B, base + 128);      // chunk 1
                unsigned ad = base + 256;  // chunk 2 address
                #pragma unroll 1
                for (int k = 0; k < 10; k++) {
                    ISSUE_C, ad);          // chunk 3k+2
                    WAIT15; ADD_A;         // chunk 3k   (wait-15 certifies it)
                    ISSUE_A, ad + 128);    // chunk 3k+3
                    WAIT15; ADD_B;         // chunk 3k+1
                    ISSUE_B, ad + 256);    // chunk 3k+4
                    WAIT15; ADD_C;         // chunk 3k+2
                    ad += 384;
                }
                WAIT8;  ADD_A;             // chunk 30 (8 newer = chunk 31)
                WAIT0;  ADD_B;             // chunk 31
            } else if (tid >= 64 && t + 1 < NT) {
                // stagers: load + transpose next tile into the other buffer
                int st = tid - 64;
                const float* src = xr + (size_t)(t + 1) * TILE;
                for (int f = st; f < TILE / 4; f += 192) {
                    float4 v4 = ((const float4*)src)[f];
                    #pragma unroll
                    for (int q = 0; q < 4; q++) {
                        int g = f * 4 + q;
                        float v = (&v4.x)[q];
                        if (mode) { float c = __fsub_rn(v, mean); v = __fmul_rn(c, c); }
                        buf[(t + 1) & 1][g & 7][g >> 3] = v;
                    }
                }
            }
            __syncthreads();
        }
        if (tid < VF) partial[tid] = p;
        __syncthreads();
        if (tid == 0) {
            float tr[VF];
            for (int j = 0; j < VF; j++) tr[j] = partial[j];
            for (int w = VF / 2; w >= 1; w >>= 1)
                for (int j = 0; j < w; j++) tr[j] = __fadd_rn(tr[j], tr[j + w]);
            float S = tr[0];
            if (mode == 0) {
                mean_sh = __fdiv_rn(S, 262144.0f);
            } else {
                float var = __fdiv_rn(S, 262143.0f);
                float sd  = __fsqrt_rn(var);
                beta_out[row] = __fdiv_rn(sd, (float)(0.1 + 1e-6));
            }
        }
        __syncthreads();
    }
}

// ================= exact MSB radix-select (4 x 8-bit digits) =================
__device__ const unsigned pass_himask[4] = {0x00000000u, 0xFF000000u, 0xFFFF0000u, 0xFFFFFF00u};
__device__ const int      pass_shift[4]  = {24, 16, 8, 0};

// pass 0: vectorized key build (x4 + g4), acts cache write, zero-skip hist
__global__ void k_hist0(const float* __restrict__ x, const float* __restrict__ u,
                        const float* __restrict__ g, const float* __restrict__ beta,
                        float* __restrict__ acts_out, unsigned* __restrict__ cnt) {
    __shared__ unsigned lh[256];
    int row = blockIdx.x >> 4, blk = blockIdx.x & 15;
    lh[threadIdx.x] = 0;
    __syncthreads();
    float bt = beta[row];
    size_t base4 = ((size_t)row * NPB + (size_t)blk * (NPB / 16)) / 4;
    const float4* x4 = (const float4*)x;
    const float4* g4 = (const float4*)g;
    float4* a4 = (float4*)acts_out;
    unsigned zc = 0;
    for (int i = threadIdx.x; i < NPB / 16 / 4; i += 256) {
        float4 xx = x4[base4 + i];
        unsigned k[4];
        if (g) {
            float4 gg = g4[base4 + i];
            k[0] = key_from_g(xx.x, gg.x, bt); k[1] = key_from_g(xx.y, gg.y, bt);
            k[2] = key_from_g(xx.z, gg.z, bt); k[3] = key_from_g(xx.w, gg.w, bt);
        } else {
            const float4 uu = ((const float4*)u)[base4 + i];
            k[0] = act_key(xx.x, uu.x, bt); k[1] = act_key(xx.y, uu.y, bt);
            k[2] = act_key(xx.z, uu.z, bt); k[3] = act_key(xx.w, uu.w, bt);
        }
        if (acts_out) {
            float4 av;
            av.x = __uint_as_float(k[0]); av.y = __uint_as_float(k[1]);
            av.z = __uint_as_float(k[2]); av.w = __uint_as_float(k[3]);
            a4[base4 + i] = av;
        }
        #pragma unroll
        for (int q = 0; q < 4; q++) {
            if (k[q]) atomicAdd(&lh[k[q] >> 24], 1u);
            else      zc++;
        }
    }
    if (zc) atomicAdd(&lh[0], zc);
    __syncthreads();
    if (lh[threadIdx.x])
        atomicAdd(&cnt[(size_t)row * 256 + threadIdx.x], lh[threadIdx.x]);
}

// passes 1-3: vectorized acts read, conditional (rare) atomics
__global__ void k_histN(const float* __restrict__ x, const float* __restrict__ u,
                        const float* __restrict__ beta, const float* __restrict__ acts_in,
                        unsigned* __restrict__ cnt, const unsigned* __restrict__ prefix, int p) {
    __shared__ unsigned lh[256];
    int row = blockIdx.x >> 4, blk = blockIdx.x & 15;
    lh[threadIdx.x] = 0;
    __syncthreads();
    unsigned pfx = prefix[row];
    unsigned hm  = pass_himask[p];
    int sh = pass_shift[p];
    size_t base = (size_t)row * NPB + (size_t)blk * (NPB / 16);
    if (acts_in) {
        const float4* a4 = (const float4*)(acts_in + base);
        for (int i = threadIdx.x; i < NPB / 16 / 4; i += 256) {
            float4 av = a4[i];
            #pragma unroll
            for (int q = 0; q < 4; q++) {
                unsigned key = __float_as_uint((&av.x)[q]);
                if ((key & hm) == pfx)
                    atomicAdd(&lh[(key >> sh) & 255u], 1u);
            }
        }
    } else {
        float bt = beta[row];
        for (int i = threadIdx.x; i < NPB / 16; i += 256) {
            unsigned key = act_key(x[base + i], u[base + i], bt);
            if ((key & hm) == pfx)
                atomicAdd(&lh[(key >> sh) & 255u], 1u);
        }
    }
    __syncthreads();
    if (lh[threadIdx.x])
        atomicAdd(&cnt[(size_t)row * 256 + threadIdx.x], lh[threadIdx.x]);
}

__global__ void k_sel(const unsigned* __restrict__ cnt, unsigned* prefix, unsigned* rank, int p) {
    if (threadIdx.x != 0) return;
    int row = blockIdx.x;
    unsigned r   = (p == 0) ? K_SEL : rank[row];
    unsigned pfx = (p == 0) ? 0u : prefix[row];
    const unsigned* h = cnt + (size_t)row * 256;
    int sh = pass_shift[p];
    unsigned c = 0;
    for (int v = 255; v >= 0; v--) {
        unsigned hv = h[v];
        if (c + hv >= r) {
            prefix[row] = pfx | ((unsigned)v << sh);
            rank[row]   = r - c;
            return;
        }
        c += hv;
    }
}

__global__ void k_write(const float* __restrict__ x, const float* __restrict__ u,
                        const float* __restrict__ beta, const float* __restrict__ acts_in,
                        const unsigned* __restrict__ prefix, float* __restrict__ out) {
    size_t e4 = (size_t)blockIdx.x * 256 + threadIdx.x;     // float4 index
    int row = (int)(e4 >> (LOG2_NPB - 2));
    unsigned kb = prefix[row];
    unsigned k[4];
    if (acts_in) {
        float4 av = ((const float4*)acts_in)[e4];
        #pragma unroll
        for (int q = 0; q < 4; q++) k[q] = __float_as_uint((&av.x)[q]);
    } else {
        float bt = beta[row];
        const float4 xx = ((const float4*)x)[e4];
        const float4 uu = ((const float4*)u)[e4];
        k[0] = act_key(xx.x, uu.x, bt); k[1] = act_key(xx.y, uu.y, bt);
        k[2] = act_key(xx.z, uu.z, bt); k[3] = act_key(xx.w, uu.w, bt);
    }
    float4 sp, mk;
    #pragma unroll
    for (int q = 0; q < 4; q++) {
        bool m = (k[q] >= kb);
        (&sp.x)[q] = m ? __uint_as_float(k[q]) : 0.0f;
        (&mk.x)[q] = m ? 1.0f : 0.0f;
    }
    ((float4*)out)[e4] = sp;
    ((float4*)(out + NTOT))[e4] = mk;
}

extern "C" void kernel_launch(void* const* d_in, const int* in_sizes, int n_in,
                              void* d_out, int out_size, void* d_ws, size_t ws_size,
                              hipStream_t stream) {
    const float* x = (const float*)d_in[0];
    const float* u = (const float*)d_in[1];
    float* out = (float*)d_out;
    char* ws = (char*)d_ws;

    float*    beta    = (float*)(ws + OFF_BETA);
    unsigned* cnt     = (unsigned*)(ws + OFF_CNT);
    unsigned* prefix  = (unsigned*)(ws + OFF_PFX);
    unsigned* rank    = (unsigned*)(ws + OFF_RANK);
    float*    acts    = (ws_size >= WS_NEED_ACTS) ? (float*)(ws + OFF_ACTS) : nullptr;
    float*    g       = (ws_size >= WS_NEED_G)    ? (float*)(ws + OFF_G)    : nullptr;

    hipMemsetAsync(ws + OFF_CNT, 0, 131328, stream);  // cnt + pfx + rank

    k_std<<<NROWS + GBLK, 256, 0, stream>>>(x, u, beta, g);

    k_hist0<<<NROWS * 16, 256, 0, stream>>>(x, u, g, beta, acts, cnt);
    k_sel  <<<NROWS, 64, 0, stream>>>(cnt, prefix, rank, 0);
    for (int p = 1; p < 4; p++) {
        k_histN<<<NROWS * 16, 256, 0, stream>>>(x, u, beta, acts,
                                                cnt + (size_t)p * NROWS * 256, prefix, p);
        k_sel  <<<NROWS, 64, 0, stream>>>(cnt + (size_t)p * NROWS * 256, prefix, rank, p);
    }

    k_write<<<NTOT / 4 / 256, 256, 0, stream>>>(x, u, beta, acts, prefix, out);
}

// Round 16
// 314.728 us; speedup vs baseline: 7.1722x; 1.0887x over previous
//
#include <hip/hip_runtime.h>

#define NROWS 32
#define NPB   262144
#define LOG2_NPB 18
#define K_SEL 13107u
#define NTOT  (NROWS * NPB)
#define VF 8

// k_std tiling
#define TILE   8192              // floats per staged tile (32 KB)
#define NT     (NPB / TILE)      // 32 tiles
#define LROW   1028              // padded LDS row; 1028*4 = 4112 B, 16B-aligned
#define GBLK   224               // g-precompute blocks appended to k_std grid
#define SLOADS 11                // ceil(2048/192) float4 loads per stager

typedef __attribute__((ext_vector_type(4))) float f32x4;

// ---------- ws layout (byte offsets) ----------
#define OFF_BETA  4224     // float[32]
#define OFF_CNT   4352     // uint[4][32][256] = 131072 (zeroed)
#define OFF_PFX   135424   // uint[32] (zeroed)
#define OFF_RANK  135552   // uint[32] (zeroed)
#define OFF_ACTS  1048576                    // float[NTOT] acts-key cache
#define OFF_G     (OFF_ACTS + (size_t)NTOT*4) // float[NTOT] g cache
#define WS_NEED_ACTS (OFF_ACTS + (size_t)NTOT * 4)
#define WS_NEED_G    (OFF_G    + (size_t)NTOT * 4)

// ======== XLA:CPU f32 log twin (GenerateVF32Log / Eigen plog, Cephes) ========
// Unfused mul+add at every MulAdd. FROZEN: bits validated round 8.
__device__ __forceinline__ float xla_logf(float xf) {
    unsigned b = __float_as_uint(xf);
    float e = (float)(int)((b >> 23) - 126u);
    float m = __uint_as_float((b & 0x007FFFFFu) | 0x3F000000u);   // [0.5,1)
    bool mk = m < 0.707106781186547524f;
    float tmp = mk ? m : 0.0f;
    if (mk) e = __fsub_rn(e, 1.0f);
    float x = __fadd_rn(__fsub_rn(m, 1.0f), tmp);
    float z  = __fmul_rn(x, x);
    float x3 = __fmul_rn(z, x);
    float y  = __fadd_rn(__fmul_rn( 7.0376836292e-2f, x), -1.1514610310e-1f);
    float y1 = __fadd_rn(__fmul_rn(-1.2420140846e-1f, x),  1.4249322787e-1f);
    float y2 = __fadd_rn(__fmul_rn( 2.0000714765e-1f, x), -2.4999993993e-1f);
    y  = __fadd_rn(__fmul_rn(y,  x),  1.1676998740e-1f);
    y1 = __fadd_rn(__fmul_rn(y1, x), -1.6668057665e-1f);
    y2 = __fadd_rn(__fmul_rn(y2, x),  3.3333331174e-1f);
    y  = __fadd_rn(__fmul_rn(y, x3), y1);
    y  = __fadd_rn(__fmul_rn(y, x3), y2);
    y  = __fmul_rn(y, x3);
    y  = __fadd_rn(__fmul_rn(e, -2.12194440e-4f), y);
    y  = __fsub_rn(y, __fmul_rn(z, 0.5f));
    x  = __fadd_rn(x, y);
    x  = __fadd_rn(__fmul_rn(e, 0.693359375f), x);
    return x;
}

__device__ __forceinline__ float g_of(float uf) {
    float i1 = xla_logf(uf);
    float i3 = xla_logf(-i1);
    return -i3;
}

__device__ __forceinline__ unsigned key_from_g(float xf, float gf, float bt) {
    float a = fmaxf(__fadd_rn(xf, __fmul_rn(bt, gf)), 0.0f);
    unsigned key = __float_as_uint(a);
    if (key == 0x80000000u) key = 0u;
    return key;
}

__device__ __forceinline__ unsigned act_key(float xf, float uf, float bt) {
    return key_from_g(xf, g_of(uf), bt);
}

// ---- inline-asm chain plumbing ----
__device__ __forceinline__ unsigned lds_addr(const void* p) {
    return (unsigned)(size_t)p;    // LDS aperture: truncation = LDS offset
}

// issue 8 ds_read_b128 (32 floats of one lane-row) from ADDR
#define ISSUE8(r0,r1,r2,r3,r4,r5,r6,r7, ADDR)                                \
    asm volatile("ds_read_b128 %0, %8 offset:0\n\t"                          \
                 "ds_read_b128 %1, %8 offset:16\n\t"                         \
                 "ds_read_b128 %2, %8 offset:32\n\t"                         \
                 "ds_read_b128 %3, %8 offset:48\n\t"                         \
                 "ds_read_b128 %4, %8 offset:64\n\t"                         \
                 "ds_read_b128 %5, %8 offset:80\n\t"                         \
                 "ds_read_b128 %6, %8 offset:96\n\t"                         \
                 "ds_read_b128 %7, %8 offset:112"                            \
                 : "=&v"(r0), "=&v"(r1), "=&v"(r2), "=&v"(r3),               \
                   "=&v"(r4), "=&v"(r5), "=&v"(r6), "=&v"(r7)                \
                 : "v"(ADDR) : "memory")

// counted waits (lgkmcnt is a 4-bit field: max literal 15); DS is in-order,
// so wait-N certifies all but the newest N DS ops have completed.
#define WAIT15 do { asm volatile("s_waitcnt lgkmcnt(15)" ::: "memory");      \
                    __builtin_amdgcn_sched_barrier(0); } while (0)
#define WAIT8  do { asm volatile("s_waitcnt lgkmcnt(8)" ::: "memory");       \
                    __builtin_amdgcn_sched_barrier(0); } while (0)
#define WAIT0  do { asm volatile("s_waitcnt lgkmcnt(0)" ::: "memory");       \
                    __builtin_amdgcn_sched_barrier(0); } while (0)

// 32 sequential __fadd_rn in ascending-address (XLA lane) order
#define ADD4(r)  do { p = __fadd_rn(p, r.x); p = __fadd_rn(p, r.y);          \
                      p = __fadd_rn(p, r.z); p = __fadd_rn(p, r.w); } while (0)
#define ADD32(r0,r1,r2,r3,r4,r5,r6,r7)                                       \
    do { ADD4(r0); ADD4(r1); ADD4(r2); ADD4(r3);                             \
         ADD4(r4); ADD4(r5); ADD4(r6); ADD4(r7); } while (0)

#define ISSUE_A ISSUE8(A0,A1,A2,A3,A4,A5,A6,A7
#define ISSUE_B ISSUE8(B0,B1,B2,B3,B4,B5,B6,B7
#define ISSUE_C ISSUE8(C0,C1,C2,C3,C4,C5,C6,C7
#define ADD_A   ADD32(A0,A1,A2,A3,A4,A5,A6,A7)
#define ADD_B   ADD32(B0,B1,B2,B3,B4,B5,B6,B7)
#define ADD_C   ADD32(C0,C1,C2,C3,C4,C5,C6,C7)

// stager: issue ALL global loads first (latency overlap), then transposed
// LDS writes. The "memory" marker pins loads above writes (T14 split).
__device__ __forceinline__ void stage_tile(const float* __restrict__ src,
                                           float (*dst)[LROW],
                                           int st, int mode, float mean) {
    float4 r[SLOADS];
    #pragma unroll
    for (int j = 0; j < SLOADS; j++) {
        int f = st + j * 192;
        if (f < TILE / 4) r[j] = ((const float4*)src)[f];
    }
    asm volatile("" ::: "memory");   // loads issued above; writes stay below
    #pragma unroll
    for (int j = 0; j < SLOADS; j++) {
        int f = st + j * 192;
        if (f < TILE / 4) {
            #pragma unroll
            for (int q = 0; q < 4; q++) {
                int g = f * 4 + q;
                float v = (&r[j].x)[q];
                if (mode) { float c = __fsub_rn(v, mean); v = __fmul_rn(c, c); }
                dst[g & 7][g >> 3] = v;
            }
        }
    }
}

// ======== k_std: XLA VF=8 reduce twin + fused g-precompute ========
// Blocks 0..31: one per row. Wave 0 lanes 0-7 run the exact sequential
// __fadd_rn chains (depth-3 asm ds_read_b128 pipeline); threads 64-255
// stage+transpose tiles into double-buffered LDS with issue-early/
// write-late global loads (the R15 bottleneck: rolled stager loop was
// latency-bound at ~1-2 loads in flight). Blocks 32+: g-precompute.
__global__ __launch_bounds__(256, 1) void k_std(const float* __restrict__ x,
                                                const float* __restrict__ u,
                                                float* __restrict__ beta_out,
                                                float* __restrict__ g_out) {
    __shared__ __align__(16) float buf[2][VF][LROW];   // 65792 B
    __shared__ float partial[VF];
    __shared__ float mean_sh;
    int tid = threadIdx.x;

    if (blockIdx.x >= NROWS) {                 // ---- g-precompute blocks ----
        if (!g_out) return;
        const float4* u4 = (const float4*)u;
        float4* g4 = (float4*)g_out;
        int idx = (blockIdx.x - NROWS) * 256 + tid;
        int stride = GBLK * 256;
        for (int i = idx; i < NTOT / 4; i += stride) {
            float4 uu = u4[i];
            float4 gg;
            gg.x = g_of(uu.x); gg.y = g_of(uu.y);
            gg.z = g_of(uu.z); gg.w = g_of(uu.w);
            g4[i] = gg;
        }
        return;
    }

    int row = blockIdx.x;
    const float* xr = x + (size_t)row * NPB;

    for (int mode = 0; mode < 2; mode++) {
        float mean = (mode == 1) ? mean_sh : 0.0f;
        // prologue: stagers (tid>=64) stage tile 0
        if (tid >= 64)
            stage_tile(xr, buf[0], tid - 64, mode, mean);
        __syncthreads();

        float p = 0.0f;
        for (int t = 0; t < NT; t++) {
            if (tid < VF) {
                // depth-3 pipeline over 32 chunks of 32 floats
                unsigned base = lds_addr(&buf[t & 1][tid][0]);
                f32x4 A0, A1, A2, A3, A4, A5, A6, A7;
                f32x4 B0, B1, B2, B3, B4, B5, B6, B7;
                f32x4 C0, C1, C2, C3, C4, C5, C6, C7;
                ISSUE_A, base);            // chunk 0
                ISSUE_B, base + 128);      // chunk 1
                unsigned ad = base + 256;  // chunk 2 address
                #pragma unroll 1
                for (int k = 0; k < 10; k++) {
                    ISSUE_C, ad);          // chunk 3k+2
                    WAIT15; ADD_A;         // chunk 3k   (wait-15 certifies it)
                    ISSUE_A, ad + 128);    // chunk 3k+3
                    WAIT15; ADD_B;         // chunk 3k+1
                    ISSUE_B, ad + 256);    // chunk 3k+4
                    WAIT15; ADD_C;         // chunk 3k+2
                    ad += 384;
                }
                WAIT8;  ADD_A;             // chunk 30 (8 newer = chunk 31)
                WAIT0;  ADD_B;             // chunk 31
            } else if (tid >= 64 && t + 1 < NT) {
                stage_tile(xr + (size_t)(t + 1) * TILE, buf[(t + 1) & 1],
                           tid - 64, mode, mean);
            }
            __syncthreads();
        }
        if (tid < VF) partial[tid] = p;
        __syncthreads();
        if (tid == 0) {
            float tr[VF];
            for (int j = 0; j < VF; j++) tr[j] = partial[j];
            for (int w = VF / 2; w >= 1; w >>= 1)
                for (int j = 0; j < w; j++) tr[j] = __fadd_rn(tr[j], tr[j + w]);
            float S = tr[0];
            if (mode == 0) {
                mean_sh = __fdiv_rn(S, 262144.0f);
            } else {
                float var = __fdiv_rn(S, 262143.0f);
                float sd  = __fsqrt_rn(var);
                beta_out[row] = __fdiv_rn(sd, (float)(0.1 + 1e-6));
            }
        }
        __syncthreads();
    }
}

// ================= exact MSB radix-select (4 x 8-bit digits) =================
__device__ const unsigned pass_himask[4] = {0x00000000u, 0xFF000000u, 0xFFFF0000u, 0xFFFFFF00u};
__device__ const int      pass_shift[4]  = {24, 16, 8, 0};

// pass 0: vectorized key build (x4 + g4), acts cache write, zero-skip hist
__global__ void k_hist0(const float* __restrict__ x, const float* __restrict__ u,
                        const float* __restrict__ g, const float* __restrict__ beta,
                        float* __restrict__ acts_out, unsigned* __restrict__ cnt) {
    __shared__ unsigned lh[256];
    int row = blockIdx.x >> 4, blk = blockIdx.x & 15;
    lh[threadIdx.x] = 0;
    __syncthreads();
    float bt = beta[row];
    size_t base4 = ((size_t)row * NPB + (size_t)blk * (NPB / 16)) / 4;
    const float4* x4 = (const float4*)x;
    const float4* g4 = (const float4*)g;
    float4* a4 = (float4*)acts_out;
    unsigned zc = 0;
    for (int i = threadIdx.x; i < NPB / 16 / 4; i += 256) {
        float4 xx = x4[base4 + i];
        unsigned k[4];
        if (g) {
            float4 gg = g4[base4 + i];
            k[0] = key_from_g(xx.x, gg.x, bt); k[1] = key_from_g(xx.y, gg.y, bt);
            k[2] = key_from_g(xx.z, gg.z, bt); k[3] = key_from_g(xx.w, gg.w, bt);
        } else {
            const float4 uu = ((const float4*)u)[base4 + i];
            k[0] = act_key(xx.x, uu.x, bt); k[1] = act_key(xx.y, uu.y, bt);
            k[2] = act_key(xx.z, uu.z, bt); k[3] = act_key(xx.w, uu.w, bt);
        }
        if (acts_out) {
            float4 av;
            av.x = __uint_as_float(k[0]); av.y = __uint_as_float(k[1]);
            av.z = __uint_as_float(k[2]); av.w = __uint_as_float(k[3]);
            a4[base4 + i] = av;
        }
        #pragma unroll
        for (int q = 0; q < 4; q++) {
            if (k[q]) atomicAdd(&lh[k[q] >> 24], 1u);
            else      zc++;
        }
    }
    if (zc) atomicAdd(&lh[0], zc);
    __syncthreads();
    if (lh[threadIdx.x])
        atomicAdd(&cnt[(size_t)row * 256 + threadIdx.x], lh[threadIdx.x]);
}

// passes 1-3: vectorized acts read, conditional (rare) atomics
__global__ void k_histN(const float* __restrict__ x, const float* __restrict__ u,
                        const float* __restrict__ beta, const float* __restrict__ acts_in,
                        unsigned* __restrict__ cnt, const unsigned* __restrict__ prefix, int p) {
    __shared__ unsigned lh[256];
    int row = blockIdx.x >> 4, blk = blockIdx.x & 15;
    lh[threadIdx.x] = 0;
    __syncthreads();
    unsigned pfx = prefix[row];
    unsigned hm  = pass_himask[p];
    int sh = pass_shift[p];
    size_t base = (size_t)row * NPB + (size_t)blk * (NPB / 16);
    if (acts_in) {
        const float4* a4 = (const float4*)(acts_in + base);
        for (int i = threadIdx.x; i < NPB / 16 / 4; i += 256) {
            float4 av = a4[i];
            #pragma unroll
            for (int q = 0; q < 4; q++) {
                unsigned key = __float_as_uint((&av.x)[q]);
                if ((key & hm) == pfx)
                    atomicAdd(&lh[(key >> sh) & 255u], 1u);
            }
        }
    } else {
        float bt = beta[row];
        for (int i = threadIdx.x; i < NPB / 16; i += 256) {
            unsigned key = act_key(x[base + i], u[base + i], bt);
            if ((key & hm) == pfx)
                atomicAdd(&lh[(key >> sh) & 255u], 1u);
        }
    }
    __syncthreads();
    if (lh[threadIdx.x])
        atomicAdd(&cnt[(size_t)row * 256 + threadIdx.x], lh[threadIdx.x]);
}

__global__ void k_sel(const unsigned* __restrict__ cnt, unsigned* prefix, unsigned* rank, int p) {
    if (threadIdx.x != 0) return;
    int row = blockIdx.x;
    unsigned r   = (p == 0) ? K_SEL : rank[row];
    unsigned pfx = (p == 0) ? 0u : prefix[row];
    const unsigned* h = cnt + (size_t)row * 256;
    int sh = pass_shift[p];
    unsigned c = 0;
    for (int v = 255; v >= 0; v--) {
        unsigned hv = h[v];
        if (c + hv >= r) {
            prefix[row] = pfx | ((unsigned)v << sh);
            rank[row]   = r - c;
            return;
        }
        c += hv;
    }
}

__global__ void k_write(const float* __restrict__ x, const float* __restrict__ u,
                        const float* __restrict__ beta, const float* __restrict__ acts_in,
                        const unsigned* __restrict__ prefix, float* __restrict__ out) {
    size_t e4 = (size_t)blockIdx.x * 256 + threadIdx.x;     // float4 index
    int row = (int)(e4 >> (LOG2_NPB - 2));
    unsigned kb = prefix[row];
    unsigned k[4];
    if (acts_in) {
        float4 av = ((const float4*)acts_in)[e4];
        #pragma unroll
        for (int q = 0; q < 4; q++) k[q] = __float_as_uint((&av.x)[q]);
    } else {
        float bt = beta[row];
        const float4 xx = ((const float4*)x)[e4];
        const float4 uu = ((const float4*)u)[e4];
        k[0] = act_key(xx.x, uu.x, bt); k[1] = act_key(xx.y, uu.y, bt);
        k[2] = act_key(xx.z, uu.z, bt); k[3] = act_key(xx.w, uu.w, bt);
    }
    float4 sp, mk;
    #pragma unroll
    for (int q = 0; q < 4; q++) {
        bool m = (k[q] >= kb);
        (&sp.x)[q] = m ? __uint_as_float(k[q]) : 0.0f;
        (&mk.x)[q] = m ? 1.0f : 0.0f;
    }
    ((float4*)out)[e4] = sp;
    ((float4*)(out + NTOT))[e4] = mk;
}

extern "C" void kernel_launch(void* const* d_in, const int* in_sizes, int n_in,
                              void* d_out, int out_size, void* d_ws, size_t ws_size,
                              hipStream_t stream) {
    const float* x = (const float*)d_in[0];
    const float* u = (const float*)d_in[1];
    float* out = (float*)d_out;
    char* ws = (char*)d_ws;

    float*    beta    = (float*)(ws + OFF_BETA);
    unsigned* cnt     = (unsigned*)(ws + OFF_CNT);
    unsigned* prefix  = (unsigned*)(ws + OFF_PFX);
    unsigned* rank    = (unsigned*)(ws + OFF_RANK);
    float*    acts    = (ws_size >= WS_NEED_ACTS) ? (float*)(ws + OFF_ACTS) : nullptr;
    float*    g       = (ws_size >= WS_NEED_G)    ? (float*)(ws + OFF_G)    : nullptr;

    hipMemsetAsync(ws + OFF_CNT, 0, 131328, stream);  // cnt + pfx + rank

    k_std<<<NROWS + GBLK, 256, 0, stream>>>(x, u, beta, g);

    k_hist0<<<NROWS * 16, 256, 0, stream>>>(x, u, g, beta, acts, cnt);
    k_sel  <<<NROWS, 64, 0, stream>>>(cnt, prefix, rank, 0);
    for (int p = 1; p < 4; p++) {
        k_histN<<<NROWS * 16, 256, 0, stream>>>(x, u, beta, acts,
                                                cnt + (size_t)p * NROWS * 256, prefix, p);
        k_sel  <<<NROWS, 64, 0, stream>>>(cnt + (size_t)p * NROWS * 256, prefix, rank, p);
    }

    k_write<<<NTOT / 4 / 256, 256, 0, stream>>>(x, u, beta, acts, prefix, out);
}